// Round 11
// baseline (332.999 us; speedup 1.0000x reference)
//
#include <hip/hip_runtime.h>
#include <hip/hip_bf16.h>

using bf16 = __hip_bfloat16;
typedef __bf16 bf16x8 __attribute__((ext_vector_type(8)));
typedef __bf16 bf16x2v __attribute__((ext_vector_type(2)));
typedef float f32x4 __attribute__((ext_vector_type(4)));
typedef float f32x16 __attribute__((ext_vector_type(16)));

#define SEQ 2048
#define DM  1024
// 0.125 * log2(e): folded into Q so scores come out of MFMA in log2 domain.
#define QSCALE 0.18033688011112042f

__device__ __forceinline__ f32x4 mfma16(bf16x8 a, bf16x8 b, f32x4 c) {
  return __builtin_amdgcn_mfma_f32_16x16x32_bf16(a, b, c, 0, 0, 0);
}
__device__ __forceinline__ f32x16 mfma32(bf16x8 a, bf16x8 b, f32x16 c) {
  return __builtin_amdgcn_mfma_f32_32x32x16_bf16(a, b, c, 0, 0, 0);
}
__device__ __forceinline__ void gload16(const void* g, void* l) {
  __builtin_amdgcn_global_load_lds(
      (const __attribute__((address_space(1))) unsigned int*)g,
      (__attribute__((address_space(3))) unsigned int*)l, 16, 0, 0);
}
__device__ __forceinline__ unsigned short bfbits(float x) {
  bf16 h = __float2bfloat16(x);
  return *reinterpret_cast<unsigned short*>(&h);
}
__device__ __forceinline__ unsigned pk2(float a, float b) {
#if __has_builtin(__builtin_amdgcn_cvt_pk_bf16_f32)
  bf16x2v r = __builtin_amdgcn_cvt_pk_bf16_f32(a, b);
  return *reinterpret_cast<unsigned*>(&r);
#else
  return (unsigned)bfbits(a) | ((unsigned)bfbits(b) << 16);
#endif
}
__device__ __forceinline__ float fexp2(float x) {
#if __has_builtin(__builtin_amdgcn_exp2f)
  return __builtin_amdgcn_exp2f(x);
#else
  return exp2f(x);
#endif
}
// v_permlane32_swap_b32 a, b: a[l>=32] <- b[l-32]; b[l<32] <- a[l+32].
__device__ __forceinline__ void plswap(unsigned& a, unsigned& b) {
  asm("v_permlane32_swap_b32 %0, %1" : "+v"(a), "+v"(b));
}

// ---------------- Fused cast pass: X and W -> frag-tiled bf16 ----------------
__global__ __launch_bounds__(256) void cast_all(const float* __restrict__ q,
                                                const float* __restrict__ k,
                                                const float* __restrict__ v,
                                                const float* __restrict__ Wq,
                                                const float* __restrict__ Wk,
                                                const float* __restrict__ Wv,
                                                const float* __restrict__ Wo,
                                                bf16* __restrict__ Lx,
                                                bf16* __restrict__ Lw,
                                                bf16* __restrict__ Lwo) {
  __shared__ float tf[64][68];
  if (blockIdx.y < 3) {
    const float* src = blockIdx.y == 0 ? q : (blockIdx.y == 1 ? k : v);
    bf16* dst = Lx + (size_t)blockIdx.y * (4096ull * 1024) + (size_t)blockIdx.x * 16384;
#pragma unroll
    for (int i = 0; i < 8; ++i) {
      int u = threadIdx.x + i * 256;
      int k32 = u >> 6, l = u & 63;
      const float* p = src + (size_t)(blockIdx.x * 16 + (l & 15)) * 1024 + k32 * 32 + (l >> 4) * 8;
      float4 a = *(const float4*)p;
      float4 b = *(const float4*)(p + 4);
      alignas(16) unsigned o[4] = {pk2(a.x, a.y), pk2(a.z, a.w), pk2(b.x, b.y), pk2(b.z, b.w)};
      *(uint4*)(dst + (size_t)u * 8) = *(const uint4*)o;
    }
    return;
  }
  const int widx = blockIdx.y - 3;
  const float* W = widx == 0 ? Wq : (widx == 1 ? Wk : (widx == 2 ? Wv : Wo));
  bf16* dst = widx < 3 ? (Lw + (size_t)widx * 1048576) : Lwo;
  const int t = threadIdx.x, bx = blockIdx.x & 15, by = blockIdx.x >> 4;
#pragma unroll
  for (int i = 0; i < 4; ++i) {
    int u = t + i * 256, r = u >> 4, c4 = u & 15;
    *(float4*)&tf[r][c4 * 4] = *(const float4*)(W + (size_t)(by * 64 + r) * 1024 + bx * 64 + c4 * 4);
  }
  __syncthreads();
#pragma unroll
  for (int i = 0; i < 2; ++i) {
    int u = t + i * 256;
    int sub = u >> 6, l = u & 63;
    int n16l = sub >> 1, k32l = sub & 1;
    int nn = n16l * 16 + (l & 15);
    int kk = k32l * 32 + (l >> 4) * 8;
    alignas(16) unsigned o[4];
#pragma unroll
    for (int p = 0; p < 4; ++p) o[p] = pk2(tf[kk + 2 * p][nn], tf[kk + 2 * p + 1][nn]);
    size_t off = ((((size_t)(bx * 4 + n16l)) * 32 + (by * 2 + k32l)) * 64 + l) * 8;
    *(uint4*)(dst + off) = *(const uint4*)o;
  }
}

// ---------------- Fused QKV GEMM: 256x128 tile, BK=32, dbuf + counted vmcnt ----------------
__global__ __launch_bounds__(512, 4) void qkv_gemm(const bf16* __restrict__ Lw,
                                                   const bf16* __restrict__ Lx,
                                                   const float* __restrict__ bq,
                                                   const float* __restrict__ bk,
                                                   const float* __restrict__ bv,
                                                   bf16* __restrict__ Lq,
                                                   bf16* __restrict__ Lk,
                                                   bf16* __restrict__ Lv) {
  __shared__ alignas(16) bf16 At[2][8192];
  __shared__ alignas(16) bf16 Bt[2][4096];
  const int t = threadIdx.x, lane = t & 63, w = t >> 6;
  const int m16 = lane & 15, g4 = lane >> 4;
  const int bid = blockIdx.x;
  const int logical = (bid & 7) * 48 + (bid >> 3);
  const int third = logical >> 7;
  const int r = logical & 127;
  const int shift = third < 2 ? 5 : 3;
  const int mt = r >> shift, nt = r & ((1 << shift) - 1);
  const int wm = w >> 1, wn = w & 1;
  const bf16* Wb = Lw + (size_t)third * 1048576;
  const bf16* Xb = Lx + (size_t)third * (4096ull * 1024);
  const bf16* Asrc = third < 2 ? Wb : Xb;
  const bf16* Bsrc = third < 2 ? Xb : Wb;
  f32x4 acc[4][4] = {};

#pragma unroll
  for (int ii = 0; ii < 3; ++ii) {
    int u = w * 3 + ii;
    if (u < 16)
      gload16(Asrc + (((size_t)(mt * 16 + u) * 32 + 0) * 64 + lane) * 8, (void*)&At[0][u * 512]);
    else
      gload16(Bsrc + (((size_t)(nt * 8 + u - 16) * 32 + 0) * 64 + lane) * 8, (void*)&Bt[0][(u - 16) * 512]);
  }

  int cur = 0;
  for (int k = 0; k < 32; ++k) {
    __builtin_amdgcn_s_barrier();
    __builtin_amdgcn_sched_barrier(0);
    if (k < 31) {
      const int nb = cur ^ 1;
#pragma unroll
      for (int ii = 0; ii < 3; ++ii) {
        int u = w * 3 + ii;
        if (u < 16)
          gload16(Asrc + (((size_t)(mt * 16 + u) * 32 + k + 1) * 64 + lane) * 8, (void*)&At[nb][u * 512]);
        else
          gload16(Bsrc + (((size_t)(nt * 8 + u - 16) * 32 + k + 1) * 64 + lane) * 8,
                  (void*)&Bt[nb][(u - 16) * 512]);
      }
      asm volatile("s_waitcnt vmcnt(3)" ::: "memory");
    } else {
      asm volatile("s_waitcnt vmcnt(0)" ::: "memory");
    }
    __builtin_amdgcn_sched_barrier(0);
    __builtin_amdgcn_s_barrier();
    __builtin_amdgcn_sched_barrier(0);

    bf16x8 afr[4], bfr[4];
#pragma unroll
    for (int i = 0; i < 4; ++i) afr[i] = *(const bf16x8*)&At[cur][(wm * 4 + i) * 512 + lane * 8];
#pragma unroll
    for (int j = 0; j < 4; ++j) bfr[j] = *(const bf16x8*)&Bt[cur][(wn * 4 + j) * 512 + lane * 8];
    __builtin_amdgcn_s_setprio(1);
#pragma unroll
    for (int i = 0; i < 4; ++i)
#pragma unroll
      for (int j = 0; j < 4; ++j) acc[i][j] = mfma16(afr[i], bfr[j], acc[i][j]);
    __builtin_amdgcn_s_setprio(0);
    cur ^= 1;
  }

  if (third < 2) {
    bf16* dst = third == 0 ? Lq : Lk;
    const float* bias = third == 0 ? bq : bk;
    const float sc = third == 0 ? QSCALE : 1.0f;
#pragma unroll
    for (int mi = 0; mi < 4; ++mi) {
      int doutb = mt * 256 + wm * 64 + mi * 16 + g4 * 4;
      float4 b4 = *(const float4*)(bias + doutb);
      int hh = doutb >> 6, d32 = (doutb & 63) >> 5;
      int lhi = (doutb & 31) >> 3, half = g4 & 1;
#pragma unroll
      for (int nj = 0; nj < 4; ++nj) {
        int seq = nt * 128 + wn * 64 + nj * 16 + m16;
        int bb2 = seq >> 11, s16w = (seq & 2047) >> 4;
        size_t off = ((((size_t)(bb2 * 128 + s16w)) * 16 + hh) * 2 + d32) * 512 + (m16 + 16 * lhi) * 8 + half * 4;
        uint2 pv;
        pv.x = pk2((acc[mi][nj][0] + b4.x) * sc, (acc[mi][nj][1] + b4.y) * sc);
        pv.y = pk2((acc[mi][nj][2] + b4.z) * sc, (acc[mi][nj][3] + b4.w) * sc);
        *(uint2*)(dst + off) = pv;
      }
    }
  } else {
#pragma unroll
    for (int nj = 0; nj < 4; ++nj) {
      int dout = nt * 128 + wn * 64 + nj * 16 + m16;
      float bvv = bv[dout];
      int hh = dout >> 6, dt = (dout & 63) >> 4;
#pragma unroll
      for (int mi = 0; mi < 4; ++mi) {
        int seqb = mt * 256 + wm * 64 + mi * 16 + g4 * 4;
        int b_ = seqb >> 11, kt = (seqb & 2047) >> 6, ks32 = (seqb & 63) >> 5;
        int lhi = (seqb & 31) >> 3, half = g4 & 1;
        size_t off = (((((size_t)(b_ * 32 + kt)) * 16 + hh) * 4 + dt) * 2 + ks32) * 512 + (m16 + 16 * lhi) * 8 + half * 4;
        uint2 pv;
        pv.x = pk2(acc[mi][nj][0] + bvv, acc[mi][nj][1] + bvv);
        pv.y = pk2(acc[mi][nj][2] + bvv, acc[mi][nj][3] + bvv);
        *(uint2*)(Lv + off) = pv;
      }
    }
  }
}

// ---------------- Flash attention: split-K across blocks, 32 waves/CU ----------------
// Block = 128 q x 1024 keys (key-half kh); 8 waves = 4 qwarps x 2 streams of 512
// keys (16 steps x 32 keys). LDS 33KB, VGPR<=64 -> 4 blocks/CU = 32 waves/CU.
// m==0 softmax => cross-block combine is a pure (O,l) sum. R10 bug fixed here:
// lpart is per-(kh, q, h) — the softmax sum depends on the head; the old [kh][q]
// index made 16 h-blocks race on one slot.
__global__ __launch_bounds__(512, 8) void flash(const bf16* __restrict__ Lq,
                                                const bf16* __restrict__ Lk,
                                                const bf16* __restrict__ Lv,
                                                float* __restrict__ Op0,
                                                float* __restrict__ Op1,
                                                float* __restrict__ lpart) {
  // [0,16384) K: [g 2][buf 2][2048 bf16]; [16384,32768) V same shape.
  // post-loop overlay: [0,32768) Os f32 [8][16][64]; [32768,33280) Ls f32 [4][32]
  __shared__ alignas(16) unsigned char smem[33280];
  bf16* const Kb = (bf16*)smem;
  bf16* const Vb = (bf16*)(smem + 16384);

  const int t = threadIdx.x, lane = t & 63, w = t >> 6;
  const int l31 = lane & 31, m16 = lane & 15, hi = lane >> 5, b4 = (lane >> 4) & 1;
  const int qw = w >> 1, g = w & 1, wg = w >> 1;
  // bijective XCD swizzle over grid 1024 = 8 * 128; logical = [b][h][qt][kh]
  const int bid = blockIdx.x;
  const int logical = ((bid & 7) << 7) | (bid >> 3);
  const int kh = logical & 1, qt = (logical >> 1) & 15, h = (logical >> 5) & 15, b = logical >> 9;

  const int sQ = b * 128 + qt * 8 + qw * 2 + b4;
  bf16x8 qf[4];
#pragma unroll
  for (int ks = 0; ks < 4; ++ks) {
    const int d32 = ks >> 1, g4q = (ks & 1) * 2 + hi;
    qf[ks] = *(const bf16x8*)(Lq + (((size_t)sQ * 16 + h) * 2 + d32) * 512 + (m16 + 16 * g4q) * 8);
  }

  const int ss = wg >> 1, sd = wg & 1;
  const int s16base = b * 128 + kh * 64 + g * 32;  // stream's 512-key range, s16 units
  const int ktbase = kh * 16 + g * 8;              // 64-key kt units
  // stage step 0
  {
    const bf16* gk = Lk + ((((size_t)(s16base + ss)) * 16 + h) * 2 + sd) * 512 + lane * 8;
    gload16(gk, (void*)(Kb + (g * 2 + 0) * 2048 + wg * 512));
    const bf16* gv = Lv + (((((size_t)(b * 32 + ktbase)) * 16 + h) * 4 + wg) * 2 + 0) * 512 + lane * 8;
    gload16(gv, (void*)(Vb + (g * 2 + 0) * 2048 + wg * 512));
  }

  float lrow = 0.f;
  f32x16 oacc[2] = {};
  __syncthreads();

  for (int it = 0; it < 16; ++it) {
    const int cur = it & 1;
    const bf16* const Kl = Kb + (g * 2 + cur) * 2048;
    const bf16* const Vl = Vb + (g * 2 + cur) * 2048;
    if (it < 15) {
      const int nb = cur ^ 1, kc = it + 1;
      const bf16* gk = Lk + ((((size_t)(s16base + kc * 2 + ss)) * 16 + h) * 2 + sd) * 512 + lane * 8;
      gload16(gk, (void*)(Kb + (g * 2 + nb) * 2048 + wg * 512));
      const bf16* gv = Lv + (((((size_t)(b * 32 + ktbase + (kc >> 1))) * 16 + h) * 4 + wg) * 2 + (kc & 1)) * 512 + lane * 8;
      gload16(gv, (void*)(Vb + (g * 2 + nb) * 2048 + wg * 512));
    }

    // S^T[key32][q32] over d=64
    f32x16 s = {};
    __builtin_amdgcn_s_setprio(1);
#pragma unroll
    for (int ks = 0; ks < 4; ++ks) {
      const int d32 = ks >> 1, g4k = (ks & 1) * 2 + hi;
      bf16x8 kf = *(const bf16x8*)&Kl[((b4 * 2 + d32) * 64 + m16 + 16 * g4k) * 8];
      s = mfma32(kf, qf[ks], s);
    }
    __builtin_amdgcn_s_setprio(0);

    float e[16];
#pragma unroll
    for (int r = 0; r < 16; ++r) e[r] = fexp2(s[r]);
    {
      float a0 = e[0] + e[1], a1 = e[2] + e[3], a2 = e[4] + e[5], a3 = e[6] + e[7];
      float a4 = e[8] + e[9], a5 = e[10] + e[11], a6 = e[12] + e[13], a7 = e[14] + e[15];
      lrow += ((a0 + a1) + (a2 + a3)) + ((a4 + a5) + (a6 + a7));
    }
    bf16x8 bP[2];
#pragma unroll
    for (int c = 0; c < 2; ++c) {
      unsigned P0 = pk2(e[8 * c + 0], e[8 * c + 1]);
      unsigned P1 = pk2(e[8 * c + 2], e[8 * c + 3]);
      unsigned P2 = pk2(e[8 * c + 4], e[8 * c + 5]);
      unsigned P3 = pk2(e[8 * c + 6], e[8 * c + 7]);
      plswap(P0, P2);
      plswap(P1, P3);
      alignas(16) unsigned pw[4] = {P0, P1, P2, P3};
      bP[c] = *(const bf16x8*)pw;
    }

    __builtin_amdgcn_s_setprio(1);
#pragma unroll
    for (int dtile = 0; dtile < 2; ++dtile) {
      const int dt = dtile * 2 + b4;
#pragma unroll
      for (int c = 0; c < 2; ++c) {
        bf16x8 av = *(const bf16x8*)&Vl[(dt * 64 + m16 + 16 * (2 * c + hi)) * 8];
        oacc[dtile] = mfma32(av, bP[c], oacc[dtile]);
      }
    }
    __builtin_amdgcn_s_setprio(0);
    __syncthreads();
  }

  // per-q l over this block's 1024 keys
  lrow += __shfl_xor(lrow, 32);

  float* const Os = (float*)smem;              // [8][16][64]
  float* const Ls = (float*)(smem + 32768);    // [4][32]
  if (g == 1) {
#pragma unroll
    for (int dtile = 0; dtile < 2; ++dtile)
#pragma unroll
      for (int r = 0; r < 16; ++r)
        Os[((qw * 2 + dtile) * 16 + r) * 64 + lane] = oacc[dtile][r];
    if (hi == 0) Ls[qw * 32 + l31] = lrow;
  }
  __syncthreads();
  if (g == 0) {
    const float lsum = lrow + Ls[qw * 32 + l31];
    float* const Op = kh ? Op1 : Op0;
    // l is per (q, h): index [kh][q][h] (R10 raced on [kh][q])
    if (hi == 0) lpart[(((kh * 4096) + sQ * 16 + m16) << 4) + h] = lsum;
#pragma unroll
    for (int dtile = 0; dtile < 2; ++dtile) {
      const int k32 = h * 2 + dtile;
#pragma unroll
      for (int j = 0; j < 8; ++j) {
        const int r = 2 * j;
        float o0 = oacc[dtile][r] + Os[((qw * 2 + dtile) * 16 + r) * 64 + lane];
        float o1 = oacc[dtile][r + 1] + Os[((qw * 2 + dtile) * 16 + r + 1) * 64 + lane];
        size_t off = ((size_t)sQ * 32 + k32) * 512 + (m16 + 16 * (r >> 2)) * 8 + 4 * hi + (r & 3);
        float2 pv;
        pv.x = o0;
        pv.y = o1;
        *(float2*)(Op + off) = pv;
      }
    }
  }
}

// ---------------- Combine: sum key-half partials, normalize, emit Lab bf16 ----------------
// slot s covers Lab bf16 elements {2s, 2s+1}; Opart holds the matching fp32 pair.
__global__ __launch_bounds__(256) void combine(const float* __restrict__ Op0,
                                               const float* __restrict__ Op1,
                                               const float* __restrict__ lpart,
                                               bf16* __restrict__ Lab) {
  const int s = blockIdx.x * 256 + threadIdx.x;   // 2'097'152 slots
  const size_t off = (size_t)s * 2;
  const int w8 = (int)(off & 511);
  const int sQ = (int)(off >> 14);
  const int k32 = (int)((off >> 9) & 31);
  const int h = k32 >> 1;
  const int m16 = (w8 >> 3) & 15;
  const int q = sQ * 16 + m16;
  const float inv = 1.f / (lpart[(q << 4) + h] + lpart[((4096 + q) << 4) + h]);
  float2 a = *(const float2*)(Op0 + off);
  float2 b = *(const float2*)(Op1 + off);
  *(unsigned*)(Lab + off) = pk2((a.x + b.x) * inv, (a.y + b.y) * inv);
}

// ---------------- Final GEMM: dbuf + counted vmcnt, XCD swizzle ----------------
__global__ __launch_bounds__(256) void out_gemm(const bf16* __restrict__ Lab,
                                                const bf16* __restrict__ Lwo,
                                                const float* __restrict__ bo,
                                                float* __restrict__ out) {
  __shared__ alignas(16) bf16 Al[2][8192];
  __shared__ alignas(16) bf16 Bl[2][4096];
  const int t = threadIdx.x, lane = t & 63, w = t >> 6;
  const int m16 = lane & 15, g4 = lane >> 4;
  const int bid = blockIdx.y * 16 + blockIdx.x;
  const int logical = (bid & 7) * 64 + (bid >> 3);
  const int nt = logical & 15, mt = logical >> 4;
  const int wm = w >> 1, wn = w & 1;
  f32x4 acc[4][2] = {};

#pragma unroll
  for (int ii = 0; ii < 4; ++ii) {
    int s = w * 4 + ii;
    gload16(Lab + (((size_t)(mt * 8 + (s >> 1))) * 32 + (s & 1)) * 512 + lane * 8, (void*)&Al[0][s * 512]);
  }
#pragma unroll
  for (int ii = 0; ii < 2; ++ii) {
    int s = w * 2 + ii;
    gload16(Lwo + (((size_t)(nt * 4 + (s >> 1))) * 32 + (s & 1)) * 512 + lane * 8, (void*)&Bl[0][s * 512]);
  }

  int cur = 0;
  for (int slab = 0; slab < 16; ++slab) {
    __builtin_amdgcn_s_barrier();
    __builtin_amdgcn_sched_barrier(0);
    if (slab < 15) {
      const int nb = cur ^ 1, ns = slab + 1;
#pragma unroll
      for (int ii = 0; ii < 4; ++ii) {
        int s = w * 4 + ii;
        gload16(Lab + (((size_t)(mt * 8 + (s >> 1))) * 32 + ns * 2 + (s & 1)) * 512 + lane * 8,
                (void*)&Al[nb][s * 512]);
      }
#pragma unroll
      for (int ii = 0; ii < 2; ++ii) {
        int s = w * 2 + ii;
        gload16(Lwo + (((size_t)(nt * 4 + (s >> 1))) * 32 + ns * 2 + (s & 1)) * 512 + lane * 8,
                (void*)&Bl[nb][s * 512]);
      }
      asm volatile("s_waitcnt vmcnt(6)" ::: "memory");
    } else {
      asm volatile("s_waitcnt vmcnt(0)" ::: "memory");
    }
    __builtin_amdgcn_sched_barrier(0);
    __builtin_amdgcn_s_barrier();
    __builtin_amdgcn_sched_barrier(0);
#pragma unroll
    for (int c = 0; c < 2; ++c) {
      bf16x8 aA[4], bW[2];
#pragma unroll
      for (int i = 0; i < 4; ++i) aA[i] = *(const bf16x8*)&Al[cur][((wm * 4 + i) * 2 + c) * 512 + lane * 8];
#pragma unroll
      for (int j = 0; j < 2; ++j) bW[j] = *(const bf16x8*)&Bl[cur][((wn * 2 + j) * 2 + c) * 512 + lane * 8];
      __builtin_amdgcn_s_setprio(1);
#pragma unroll
      for (int i = 0; i < 4; ++i)
#pragma unroll
        for (int j = 0; j < 2; ++j) acc[i][j] = mfma16(aA[i], bW[j], acc[i][j]);
      __builtin_amdgcn_s_setprio(0);
    }
    cur ^= 1;
  }
#pragma unroll
  for (int j = 0; j < 2; ++j) {
    int n = nt * 64 + wn * 32 + j * 16 + m16;
    float bb = bo[n];
#pragma unroll
    for (int i = 0; i < 4; ++i) {
      int seqb = mt * 128 + wm * 64 + i * 16 + g4 * 4;
#pragma unroll
      for (int r = 0; r < 4; ++r) out[(size_t)(seqb + r) * 1024 + n] = acc[i][j][r] + bb;
    }
  }
}

extern "C" void kernel_launch(void* const* d_in, const int* in_sizes, int n_in,
                              void* d_out, int out_size, void* d_ws, size_t ws_size,
                              hipStream_t stream) {
  const float* query = (const float*)d_in[0];
  const float* key   = (const float*)d_in[1];
  const float* value = (const float*)d_in[2];
  const float* Wq = (const float*)d_in[3];
  const float* bq = (const float*)d_in[4];
  const float* Wk = (const float*)d_in[5];
  const float* bk = (const float*)d_in[6];
  const float* Wv = (const float*)d_in[7];
  const float* bv = (const float*)d_in[8];
  const float* Wo = (const float*)d_in[9];
  const float* bo = (const float*)d_in[10];
  float* out = (float*)d_out;

  bf16* Lw  = (bf16*)d_ws;
  bf16* Lwo = Lw + 3ull * 1048576;
  bf16* Lx  = Lwo + 1048576;
  bf16* Lq  = Lx + 3ull * 4194304;
  bf16* Lk  = Lq + 4194304;
  bf16* Lv  = Lk + 4194304;
  bf16* Lab = Lv + 4194304;

  // scratch for flash partials: Lx is dead after qkv_gemm; d_out is free until out_gemm
  float* Op0   = out;                        // kh=0 partial O (16.8MB)
  float* Op1   = (float*)Lx;                 // kh=1 partial O (16.8MB, fits in Lx's 24MB)
  float* lpart = (float*)Lx + 4194304;       // [kh 2][q 4096][h 16] f32 = 512KB

  cast_all<<<dim3(256, 7), 256, 0, stream>>>(query, key, value, Wq, Wk, Wv, Wo, Lx, Lw, Lwo);
  qkv_gemm<<<384, 512, 0, stream>>>(Lw, Lx, bq, bk, bv, Lq, Lk, Lv);
  flash<<<1024, 512, 0, stream>>>(Lq, Lk, Lv, Op0, Op1, lpart);
  combine<<<8192, 256, 0, stream>>>(Op0, Op1, lpart, Lab);
  out_gemm<<<dim3(16, 32), 256, 0, stream>>>(Lab, Lwo, bo, out);
}

// Round 12
// 223.953 us; speedup vs baseline: 1.4869x; 1.4869x over previous
//
#include <hip/hip_runtime.h>
#include <hip/hip_bf16.h>

using bf16 = __hip_bfloat16;
typedef __bf16 bf16x8 __attribute__((ext_vector_type(8)));
typedef __bf16 bf16x2v __attribute__((ext_vector_type(2)));
typedef float f32x4 __attribute__((ext_vector_type(4)));
typedef float f32x16 __attribute__((ext_vector_type(16)));

#define SEQ 2048
#define DM  1024
// 0.125 * log2(e): folded into Q so scores come out of MFMA in log2 domain.
#define QSCALE 0.18033688011112042f

__device__ __forceinline__ f32x4 mfma16(bf16x8 a, bf16x8 b, f32x4 c) {
  return __builtin_amdgcn_mfma_f32_16x16x32_bf16(a, b, c, 0, 0, 0);
}
__device__ __forceinline__ f32x16 mfma32(bf16x8 a, bf16x8 b, f32x16 c) {
  return __builtin_amdgcn_mfma_f32_32x32x16_bf16(a, b, c, 0, 0, 0);
}
__device__ __forceinline__ void gload16(const void* g, void* l) {
  __builtin_amdgcn_global_load_lds(
      (const __attribute__((address_space(1))) unsigned int*)g,
      (__attribute__((address_space(3))) unsigned int*)l, 16, 0, 0);
}
__device__ __forceinline__ unsigned short bfbits(float x) {
  bf16 h = __float2bfloat16(x);
  return *reinterpret_cast<unsigned short*>(&h);
}
__device__ __forceinline__ unsigned pk2(float a, float b) {
#if __has_builtin(__builtin_amdgcn_cvt_pk_bf16_f32)
  bf16x2v r = __builtin_amdgcn_cvt_pk_bf16_f32(a, b);
  return *reinterpret_cast<unsigned*>(&r);
#else
  return (unsigned)bfbits(a) | ((unsigned)bfbits(b) << 16);
#endif
}
__device__ __forceinline__ float fexp2(float x) {
#if __has_builtin(__builtin_amdgcn_exp2f)
  return __builtin_amdgcn_exp2f(x);
#else
  return exp2f(x);
#endif
}
// v_permlane32_swap_b32 a, b: a[l>=32] <- b[l-32]; b[l<32] <- a[l+32].
__device__ __forceinline__ void plswap(unsigned& a, unsigned& b) {
  asm("v_permlane32_swap_b32 %0, %1" : "+v"(a), "+v"(b));
}

// ---------------- Fused cast pass: X and W -> frag-tiled bf16 ----------------
__global__ __launch_bounds__(256) void cast_all(const float* __restrict__ q,
                                                const float* __restrict__ k,
                                                const float* __restrict__ v,
                                                const float* __restrict__ Wq,
                                                const float* __restrict__ Wk,
                                                const float* __restrict__ Wv,
                                                const float* __restrict__ Wo,
                                                bf16* __restrict__ Lx,
                                                bf16* __restrict__ Lw,
                                                bf16* __restrict__ Lwo) {
  __shared__ float tf[64][68];
  if (blockIdx.y < 3) {
    const float* src = blockIdx.y == 0 ? q : (blockIdx.y == 1 ? k : v);
    bf16* dst = Lx + (size_t)blockIdx.y * (4096ull * 1024) + (size_t)blockIdx.x * 16384;
#pragma unroll
    for (int i = 0; i < 8; ++i) {
      int u = threadIdx.x + i * 256;
      int k32 = u >> 6, l = u & 63;
      const float* p = src + (size_t)(blockIdx.x * 16 + (l & 15)) * 1024 + k32 * 32 + (l >> 4) * 8;
      float4 a = *(const float4*)p;
      float4 b = *(const float4*)(p + 4);
      alignas(16) unsigned o[4] = {pk2(a.x, a.y), pk2(a.z, a.w), pk2(b.x, b.y), pk2(b.z, b.w)};
      *(uint4*)(dst + (size_t)u * 8) = *(const uint4*)o;
    }
    return;
  }
  const int widx = blockIdx.y - 3;
  const float* W = widx == 0 ? Wq : (widx == 1 ? Wk : (widx == 2 ? Wv : Wo));
  bf16* dst = widx < 3 ? (Lw + (size_t)widx * 1048576) : Lwo;
  const int t = threadIdx.x, bx = blockIdx.x & 15, by = blockIdx.x >> 4;
#pragma unroll
  for (int i = 0; i < 4; ++i) {
    int u = t + i * 256, r = u >> 4, c4 = u & 15;
    *(float4*)&tf[r][c4 * 4] = *(const float4*)(W + (size_t)(by * 64 + r) * 1024 + bx * 64 + c4 * 4);
  }
  __syncthreads();
#pragma unroll
  for (int i = 0; i < 2; ++i) {
    int u = t + i * 256;
    int sub = u >> 6, l = u & 63;
    int n16l = sub >> 1, k32l = sub & 1;
    int nn = n16l * 16 + (l & 15);
    int kk = k32l * 32 + (l >> 4) * 8;
    alignas(16) unsigned o[4];
#pragma unroll
    for (int p = 0; p < 4; ++p) o[p] = pk2(tf[kk + 2 * p][nn], tf[kk + 2 * p + 1][nn]);
    size_t off = ((((size_t)(bx * 4 + n16l)) * 32 + (by * 2 + k32l)) * 64 + l) * 8;
    *(uint4*)(dst + off) = *(const uint4*)o;
  }
}

// ---------------- Fused QKV GEMM: 256x128 tile, BK=32, dbuf + counted vmcnt ----------------
__global__ __launch_bounds__(512, 4) void qkv_gemm(const bf16* __restrict__ Lw,
                                                   const bf16* __restrict__ Lx,
                                                   const float* __restrict__ bq,
                                                   const float* __restrict__ bk,
                                                   const float* __restrict__ bv,
                                                   bf16* __restrict__ Lq,
                                                   bf16* __restrict__ Lk,
                                                   bf16* __restrict__ Lv) {
  __shared__ alignas(16) bf16 At[2][8192];
  __shared__ alignas(16) bf16 Bt[2][4096];
  const int t = threadIdx.x, lane = t & 63, w = t >> 6;
  const int m16 = lane & 15, g4 = lane >> 4;
  const int bid = blockIdx.x;
  const int logical = (bid & 7) * 48 + (bid >> 3);
  const int third = logical >> 7;
  const int r = logical & 127;
  const int shift = third < 2 ? 5 : 3;
  const int mt = r >> shift, nt = r & ((1 << shift) - 1);
  const int wm = w >> 1, wn = w & 1;
  const bf16* Wb = Lw + (size_t)third * 1048576;
  const bf16* Xb = Lx + (size_t)third * (4096ull * 1024);
  const bf16* Asrc = third < 2 ? Wb : Xb;
  const bf16* Bsrc = third < 2 ? Xb : Wb;
  f32x4 acc[4][4] = {};

#pragma unroll
  for (int ii = 0; ii < 3; ++ii) {
    int u = w * 3 + ii;
    if (u < 16)
      gload16(Asrc + (((size_t)(mt * 16 + u) * 32 + 0) * 64 + lane) * 8, (void*)&At[0][u * 512]);
    else
      gload16(Bsrc + (((size_t)(nt * 8 + u - 16) * 32 + 0) * 64 + lane) * 8, (void*)&Bt[0][(u - 16) * 512]);
  }

  int cur = 0;
  for (int k = 0; k < 32; ++k) {
    __builtin_amdgcn_s_barrier();
    __builtin_amdgcn_sched_barrier(0);
    if (k < 31) {
      const int nb = cur ^ 1;
#pragma unroll
      for (int ii = 0; ii < 3; ++ii) {
        int u = w * 3 + ii;
        if (u < 16)
          gload16(Asrc + (((size_t)(mt * 16 + u) * 32 + k + 1) * 64 + lane) * 8, (void*)&At[nb][u * 512]);
        else
          gload16(Bsrc + (((size_t)(nt * 8 + u - 16) * 32 + k + 1) * 64 + lane) * 8,
                  (void*)&Bt[nb][(u - 16) * 512]);
      }
      asm volatile("s_waitcnt vmcnt(3)" ::: "memory");
    } else {
      asm volatile("s_waitcnt vmcnt(0)" ::: "memory");
    }
    __builtin_amdgcn_sched_barrier(0);
    __builtin_amdgcn_s_barrier();
    __builtin_amdgcn_sched_barrier(0);

    bf16x8 afr[4], bfr[4];
#pragma unroll
    for (int i = 0; i < 4; ++i) afr[i] = *(const bf16x8*)&At[cur][(wm * 4 + i) * 512 + lane * 8];
#pragma unroll
    for (int j = 0; j < 4; ++j) bfr[j] = *(const bf16x8*)&Bt[cur][(wn * 4 + j) * 512 + lane * 8];
    __builtin_amdgcn_s_setprio(1);
#pragma unroll
    for (int i = 0; i < 4; ++i)
#pragma unroll
      for (int j = 0; j < 4; ++j) acc[i][j] = mfma16(afr[i], bfr[j], acc[i][j]);
    __builtin_amdgcn_s_setprio(0);
    cur ^= 1;
  }

  if (third < 2) {
    bf16* dst = third == 0 ? Lq : Lk;
    const float* bias = third == 0 ? bq : bk;
    const float sc = third == 0 ? QSCALE : 1.0f;
#pragma unroll
    for (int mi = 0; mi < 4; ++mi) {
      int doutb = mt * 256 + wm * 64 + mi * 16 + g4 * 4;
      float4 b4 = *(const float4*)(bias + doutb);
      int hh = doutb >> 6, d32 = (doutb & 63) >> 5;
      int lhi = (doutb & 31) >> 3, half = g4 & 1;
#pragma unroll
      for (int nj = 0; nj < 4; ++nj) {
        int seq = nt * 128 + wn * 64 + nj * 16 + m16;
        int bb2 = seq >> 11, s16w = (seq & 2047) >> 4;
        size_t off = ((((size_t)(bb2 * 128 + s16w)) * 16 + hh) * 2 + d32) * 512 + (m16 + 16 * lhi) * 8 + half * 4;
        uint2 pv;
        pv.x = pk2((acc[mi][nj][0] + b4.x) * sc, (acc[mi][nj][1] + b4.y) * sc);
        pv.y = pk2((acc[mi][nj][2] + b4.z) * sc, (acc[mi][nj][3] + b4.w) * sc);
        *(uint2*)(dst + off) = pv;
      }
    }
  } else {
#pragma unroll
    for (int nj = 0; nj < 4; ++nj) {
      int dout = nt * 128 + wn * 64 + nj * 16 + m16;
      float bvv = bv[dout];
      int hh = dout >> 6, dt = (dout & 63) >> 4;
#pragma unroll
      for (int mi = 0; mi < 4; ++mi) {
        int seqb = mt * 256 + wm * 64 + mi * 16 + g4 * 4;
        int b_ = seqb >> 11, kt = (seqb & 2047) >> 6, ks32 = (seqb & 63) >> 5;
        int lhi = (seqb & 31) >> 3, half = g4 & 1;
        size_t off = (((((size_t)(b_ * 32 + kt)) * 16 + hh) * 4 + dt) * 2 + ks32) * 512 + (m16 + 16 * lhi) * 8 + half * 4;
        uint2 pv;
        pv.x = pk2(acc[mi][nj][0] + bvv, acc[mi][nj][1] + bvv);
        pv.y = pk2(acc[mi][nj][2] + bvv, acc[mi][nj][3] + bvv);
        *(uint2*)(Lv + off) = pv;
      }
    }
  }
}

// ---------------- Flash attention: split-K across blocks ----------------
// Block = 128 q x 1024 keys (key-half kh); 8 waves = 4 qwarps x 2 streams of 512
// keys. LDS 33KB -> 4 blocks/CU FIT; grid 1024 = 4.0/CU. The occupancy gain
// requires VGPR <= 64. R11's (512,8) FORCED <=64 and the allocator spilled
// (VGPR=32, 463MB scratch fetch); R9's near-identical loop compiled to 56 under
// (512,4) with zero spill. So: request (512,4) (safe cap 128) and let the
// allocator land at its natural ~56 -> 4 blocks resident, no spill.
__global__ __launch_bounds__(512, 4) void flash(const bf16* __restrict__ Lq,
                                                const bf16* __restrict__ Lk,
                                                const bf16* __restrict__ Lv,
                                                float* __restrict__ Op0,
                                                float* __restrict__ Op1,
                                                float* __restrict__ lpart) {
  // [0,16384) K: [g 2][buf 2][2048 bf16]; [16384,32768) V same shape.
  // post-loop overlay: [0,32768) Os f32 [8][16][64]; [32768,33280) Ls f32 [4][32]
  __shared__ alignas(16) unsigned char smem[33280];
  bf16* const Kb = (bf16*)smem;
  bf16* const Vb = (bf16*)(smem + 16384);

  const int t = threadIdx.x, lane = t & 63, w = t >> 6;
  const int l31 = lane & 31, m16 = lane & 15, hi = lane >> 5, b4 = (lane >> 4) & 1;
  const int qw = w >> 1, g = w & 1, wg = w >> 1;
  // bijective XCD swizzle over grid 1024 = 8 * 128; logical = [b][h][qt][kh]
  const int bid = blockIdx.x;
  const int logical = ((bid & 7) << 7) | (bid >> 3);
  const int kh = logical & 1, qt = (logical >> 1) & 15, h = (logical >> 5) & 15, b = logical >> 9;

  const int sQ = b * 128 + qt * 8 + qw * 2 + b4;
  bf16x8 qf[4];
#pragma unroll
  for (int ks = 0; ks < 4; ++ks) {
    const int d32 = ks >> 1, g4q = (ks & 1) * 2 + hi;
    qf[ks] = *(const bf16x8*)(Lq + (((size_t)sQ * 16 + h) * 2 + d32) * 512 + (m16 + 16 * g4q) * 8);
  }

  const int ss = wg >> 1, sd = wg & 1;
  const int s16base = b * 128 + kh * 64 + g * 32;  // stream's 512-key range, s16 units
  const int ktbase = kh * 16 + g * 8;              // 64-key kt units
  // stage step 0
  {
    const bf16* gk = Lk + ((((size_t)(s16base + ss)) * 16 + h) * 2 + sd) * 512 + lane * 8;
    gload16(gk, (void*)(Kb + (g * 2 + 0) * 2048 + wg * 512));
    const bf16* gv = Lv + (((((size_t)(b * 32 + ktbase)) * 16 + h) * 4 + wg) * 2 + 0) * 512 + lane * 8;
    gload16(gv, (void*)(Vb + (g * 2 + 0) * 2048 + wg * 512));
  }

  float lrow = 0.f;
  f32x16 oacc[2] = {};
  __syncthreads();

  for (int it = 0; it < 16; ++it) {
    const int cur = it & 1;
    const bf16* const Kl = Kb + (g * 2 + cur) * 2048;
    const bf16* const Vl = Vb + (g * 2 + cur) * 2048;
    if (it < 15) {
      const int nb = cur ^ 1, kc = it + 1;
      const bf16* gk = Lk + ((((size_t)(s16base + kc * 2 + ss)) * 16 + h) * 2 + sd) * 512 + lane * 8;
      gload16(gk, (void*)(Kb + (g * 2 + nb) * 2048 + wg * 512));
      const bf16* gv = Lv + (((((size_t)(b * 32 + ktbase + (kc >> 1))) * 16 + h) * 4 + wg) * 2 + (kc & 1)) * 512 + lane * 8;
      gload16(gv, (void*)(Vb + (g * 2 + nb) * 2048 + wg * 512));
    }

    // S^T[key32][q32] over d=64
    f32x16 s = {};
    __builtin_amdgcn_s_setprio(1);
#pragma unroll
    for (int ks = 0; ks < 4; ++ks) {
      const int d32 = ks >> 1, g4k = (ks & 1) * 2 + hi;
      bf16x8 kf = *(const bf16x8*)&Kl[((b4 * 2 + d32) * 64 + m16 + 16 * g4k) * 8];
      s = mfma32(kf, qf[ks], s);
    }
    __builtin_amdgcn_s_setprio(0);

    float e[16];
#pragma unroll
    for (int r = 0; r < 16; ++r) e[r] = fexp2(s[r]);
    {
      float a0 = e[0] + e[1], a1 = e[2] + e[3], a2 = e[4] + e[5], a3 = e[6] + e[7];
      float a4 = e[8] + e[9], a5 = e[10] + e[11], a6 = e[12] + e[13], a7 = e[14] + e[15];
      lrow += ((a0 + a1) + (a2 + a3)) + ((a4 + a5) + (a6 + a7));
    }
    bf16x8 bP[2];
#pragma unroll
    for (int c = 0; c < 2; ++c) {
      unsigned P0 = pk2(e[8 * c + 0], e[8 * c + 1]);
      unsigned P1 = pk2(e[8 * c + 2], e[8 * c + 3]);
      unsigned P2 = pk2(e[8 * c + 4], e[8 * c + 5]);
      unsigned P3 = pk2(e[8 * c + 6], e[8 * c + 7]);
      plswap(P0, P2);
      plswap(P1, P3);
      alignas(16) unsigned pw[4] = {P0, P1, P2, P3};
      bP[c] = *(const bf16x8*)pw;
    }

    __builtin_amdgcn_s_setprio(1);
#pragma unroll
    for (int dtile = 0; dtile < 2; ++dtile) {
      const int dt = dtile * 2 + b4;
#pragma unroll
      for (int c = 0; c < 2; ++c) {
        bf16x8 av = *(const bf16x8*)&Vl[(dt * 64 + m16 + 16 * (2 * c + hi)) * 8];
        oacc[dtile] = mfma32(av, bP[c], oacc[dtile]);
      }
    }
    __builtin_amdgcn_s_setprio(0);
    __syncthreads();
  }

  // per-q l over this block's 1024 keys
  lrow += __shfl_xor(lrow, 32);

  float* const Os = (float*)smem;              // [8][16][64]
  float* const Ls = (float*)(smem + 32768);    // [4][32]
  if (g == 1) {
#pragma unroll
    for (int dtile = 0; dtile < 2; ++dtile)
#pragma unroll
      for (int r = 0; r < 16; ++r)
        Os[((qw * 2 + dtile) * 16 + r) * 64 + lane] = oacc[dtile][r];
    if (hi == 0) Ls[qw * 32 + l31] = lrow;
  }
  __syncthreads();
  if (g == 0) {
    const float lsum = lrow + Ls[qw * 32 + l31];
    float* const Op = kh ? Op1 : Op0;
    // l is per (q, h): index [kh][q][h]
    if (hi == 0) lpart[(((kh * 4096) + sQ * 16 + m16) << 4) + h] = lsum;
#pragma unroll
    for (int dtile = 0; dtile < 2; ++dtile) {
      const int k32 = h * 2 + dtile;
#pragma unroll
      for (int j = 0; j < 8; ++j) {
        const int r = 2 * j;
        float o0 = oacc[dtile][r] + Os[((qw * 2 + dtile) * 16 + r) * 64 + lane];
        float o1 = oacc[dtile][r + 1] + Os[((qw * 2 + dtile) * 16 + r + 1) * 64 + lane];
        size_t off = ((size_t)sQ * 32 + k32) * 512 + (m16 + 16 * (r >> 2)) * 8 + 4 * hi + (r & 3);
        float2 pv;
        pv.x = o0;
        pv.y = o1;
        *(float2*)(Op + off) = pv;
      }
    }
  }
}

// ---------------- Combine: sum key-half partials, normalize, emit Lab bf16 ----------------
// slot s covers Lab bf16 elements {2s, 2s+1}; Opart holds the matching fp32 pair.
__global__ __launch_bounds__(256) void combine(const float* __restrict__ Op0,
                                               const float* __restrict__ Op1,
                                               const float* __restrict__ lpart,
                                               bf16* __restrict__ Lab) {
  const int s = blockIdx.x * 256 + threadIdx.x;   // 2'097'152 slots
  const size_t off = (size_t)s * 2;
  const int w8 = (int)(off & 511);
  const int sQ = (int)(off >> 14);
  const int k32 = (int)((off >> 9) & 31);
  const int h = k32 >> 1;
  const int m16 = (w8 >> 3) & 15;
  const int q = sQ * 16 + m16;
  const float inv = 1.f / (lpart[(q << 4) + h] + lpart[((4096 + q) << 4) + h]);
  float2 a = *(const float2*)(Op0 + off);
  float2 b = *(const float2*)(Op1 + off);
  *(unsigned*)(Lab + off) = pk2((a.x + b.x) * inv, (a.y + b.y) * inv);
}

// ---------------- Final GEMM: dbuf + counted vmcnt, XCD swizzle ----------------
__global__ __launch_bounds__(256) void out_gemm(const bf16* __restrict__ Lab,
                                                const bf16* __restrict__ Lwo,
                                                const float* __restrict__ bo,
                                                float* __restrict__ out) {
  __shared__ alignas(16) bf16 Al[2][8192];
  __shared__ alignas(16) bf16 Bl[2][4096];
  const int t = threadIdx.x, lane = t & 63, w = t >> 6;
  const int m16 = lane & 15, g4 = lane >> 4;
  const int bid = blockIdx.y * 16 + blockIdx.x;
  const int logical = (bid & 7) * 64 + (bid >> 3);
  const int nt = logical & 15, mt = logical >> 4;
  const int wm = w >> 1, wn = w & 1;
  f32x4 acc[4][2] = {};

#pragma unroll
  for (int ii = 0; ii < 4; ++ii) {
    int s = w * 4 + ii;
    gload16(Lab + (((size_t)(mt * 8 + (s >> 1))) * 32 + (s & 1)) * 512 + lane * 8, (void*)&Al[0][s * 512]);
  }
#pragma unroll
  for (int ii = 0; ii < 2; ++ii) {
    int s = w * 2 + ii;
    gload16(Lwo + (((size_t)(nt * 4 + (s >> 1))) * 32 + (s & 1)) * 512 + lane * 8, (void*)&Bl[0][s * 512]);
  }

  int cur = 0;
  for (int slab = 0; slab < 16; ++slab) {
    __builtin_amdgcn_s_barrier();
    __builtin_amdgcn_sched_barrier(0);
    if (slab < 15) {
      const int nb = cur ^ 1, ns = slab + 1;
#pragma unroll
      for (int ii = 0; ii < 4; ++ii) {
        int s = w * 4 + ii;
        gload16(Lab + (((size_t)(mt * 8 + (s >> 1))) * 32 + ns * 2 + (s & 1)) * 512 + lane * 8,
                (void*)&Al[nb][s * 512]);
      }
#pragma unroll
      for (int ii = 0; ii < 2; ++ii) {
        int s = w * 2 + ii;
        gload16(Lwo + (((size_t)(nt * 4 + (s >> 1))) * 32 + ns * 2 + (s & 1)) * 512 + lane * 8,
                (void*)&Bl[nb][s * 512]);
      }
      asm volatile("s_waitcnt vmcnt(6)" ::: "memory");
    } else {
      asm volatile("s_waitcnt vmcnt(0)" ::: "memory");
    }
    __builtin_amdgcn_sched_barrier(0);
    __builtin_amdgcn_s_barrier();
    __builtin_amdgcn_sched_barrier(0);
#pragma unroll
    for (int c = 0; c < 2; ++c) {
      bf16x8 aA[4], bW[2];
#pragma unroll
      for (int i = 0; i < 4; ++i) aA[i] = *(const bf16x8*)&Al[cur][((wm * 4 + i) * 2 + c) * 512 + lane * 8];
#pragma unroll
      for (int j = 0; j < 2; ++j) bW[j] = *(const bf16x8*)&Bl[cur][((wn * 2 + j) * 2 + c) * 512 + lane * 8];
      __builtin_amdgcn_s_setprio(1);
#pragma unroll
      for (int i = 0; i < 4; ++i)
#pragma unroll
        for (int j = 0; j < 2; ++j) acc[i][j] = mfma16(aA[i], bW[j], acc[i][j]);
      __builtin_amdgcn_s_setprio(0);
    }
    cur ^= 1;
  }
#pragma unroll
  for (int j = 0; j < 2; ++j) {
    int n = nt * 64 + wn * 32 + j * 16 + m16;
    float bb = bo[n];
#pragma unroll
    for (int i = 0; i < 4; ++i) {
      int seqb = mt * 128 + wm * 64 + i * 16 + g4 * 4;
#pragma unroll
      for (int r = 0; r < 4; ++r) out[(size_t)(seqb + r) * 1024 + n] = acc[i][j][r] + bb;
    }
  }
}

extern "C" void kernel_launch(void* const* d_in, const int* in_sizes, int n_in,
                              void* d_out, int out_size, void* d_ws, size_t ws_size,
                              hipStream_t stream) {
  const float* query = (const float*)d_in[0];
  const float* key   = (const float*)d_in[1];
  const float* value = (const float*)d_in[2];
  const float* Wq = (const float*)d_in[3];
  const float* bq = (const float*)d_in[4];
  const float* Wk = (const float*)d_in[5];
  const float* bk = (const float*)d_in[6];
  const float* Wv = (const float*)d_in[7];
  const float* bv = (const float*)d_in[8];
  const float* Wo = (const float*)d_in[9];
  const float* bo = (const float*)d_in[10];
  float* out = (float*)d_out;

  bf16* Lw  = (bf16*)d_ws;
  bf16* Lwo = Lw + 3ull * 1048576;
  bf16* Lx  = Lwo + 1048576;
  bf16* Lq  = Lx + 3ull * 4194304;
  bf16* Lk  = Lq + 4194304;
  bf16* Lv  = Lk + 4194304;
  bf16* Lab = Lv + 4194304;

  // scratch for flash partials: Lx is dead after qkv_gemm; d_out is free until out_gemm
  float* Op0   = out;                        // kh=0 partial O (16.8MB)
  float* Op1   = (float*)Lx;                 // kh=1 partial O (16.8MB, fits in Lx's 24MB)
  float* lpart = (float*)Lx + 4194304;       // [kh 2][q 4096][h 16] f32 = 512KB

  cast_all<<<dim3(256, 7), 256, 0, stream>>>(query, key, value, Wq, Wk, Wv, Wo, Lx, Lw, Lwo);
  qkv_gemm<<<384, 512, 0, stream>>>(Lw, Lx, bq, bk, bv, Lq, Lk, Lv);
  flash<<<1024, 512, 0, stream>>>(Lq, Lk, Lv, Op0, Op1, lpart);
  combine<<<8192, 256, 0, stream>>>(Op0, Op1, lpart, Lab);
  out_gemm<<<dim3(16, 32), 256, 0, stream>>>(Lab, Lwo, bo, out);
}

// Round 13
// 210.977 us; speedup vs baseline: 1.5784x; 1.0615x over previous
//
#include <hip/hip_runtime.h>
#include <hip/hip_bf16.h>

using bf16 = __hip_bfloat16;
typedef __bf16 bf16x8 __attribute__((ext_vector_type(8)));
typedef __bf16 bf16x2v __attribute__((ext_vector_type(2)));
typedef float f32x4 __attribute__((ext_vector_type(4)));
typedef float f32x16 __attribute__((ext_vector_type(16)));

#define SEQ 2048
#define DM  1024
// 0.125 * log2(e): folded into Q so scores come out of MFMA in log2 domain.
#define QSCALE 0.18033688011112042f

__device__ __forceinline__ f32x4 mfma16(bf16x8 a, bf16x8 b, f32x4 c) {
  return __builtin_amdgcn_mfma_f32_16x16x32_bf16(a, b, c, 0, 0, 0);
}
__device__ __forceinline__ f32x16 mfma32(bf16x8 a, bf16x8 b, f32x16 c) {
  return __builtin_amdgcn_mfma_f32_32x32x16_bf16(a, b, c, 0, 0, 0);
}
__device__ __forceinline__ void gload16(const void* g, void* l) {
  __builtin_amdgcn_global_load_lds(
      (const __attribute__((address_space(1))) unsigned int*)g,
      (__attribute__((address_space(3))) unsigned int*)l, 16, 0, 0);
}
__device__ __forceinline__ unsigned short bfbits(float x) {
  bf16 h = __float2bfloat16(x);
  return *reinterpret_cast<unsigned short*>(&h);
}
__device__ __forceinline__ unsigned pk2(float a, float b) {
#if __has_builtin(__builtin_amdgcn_cvt_pk_bf16_f32)
  bf16x2v r = __builtin_amdgcn_cvt_pk_bf16_f32(a, b);
  return *reinterpret_cast<unsigned*>(&r);
#else
  return (unsigned)bfbits(a) | ((unsigned)bfbits(b) << 16);
#endif
}
__device__ __forceinline__ float fexp2(float x) {
#if __has_builtin(__builtin_amdgcn_exp2f)
  return __builtin_amdgcn_exp2f(x);
#else
  return exp2f(x);
#endif
}
// v_permlane32_swap_b32 a, b: a[l>=32] <- b[l-32]; b[l<32] <- a[l+32].
__device__ __forceinline__ void plswap(unsigned& a, unsigned& b) {
  asm("v_permlane32_swap_b32 %0, %1" : "+v"(a), "+v"(b));
}

// ---------------- Fused cast pass: X and W -> frag-tiled bf16 ----------------
__global__ __launch_bounds__(256) void cast_all(const float* __restrict__ q,
                                                const float* __restrict__ k,
                                                const float* __restrict__ v,
                                                const float* __restrict__ Wq,
                                                const float* __restrict__ Wk,
                                                const float* __restrict__ Wv,
                                                const float* __restrict__ Wo,
                                                bf16* __restrict__ Lx,
                                                bf16* __restrict__ Lw,
                                                bf16* __restrict__ Lwo) {
  __shared__ float tf[64][68];
  if (blockIdx.y < 3) {
    const float* src = blockIdx.y == 0 ? q : (blockIdx.y == 1 ? k : v);
    bf16* dst = Lx + (size_t)blockIdx.y * (4096ull * 1024) + (size_t)blockIdx.x * 16384;
#pragma unroll
    for (int i = 0; i < 8; ++i) {
      int u = threadIdx.x + i * 256;
      int k32 = u >> 6, l = u & 63;
      const float* p = src + (size_t)(blockIdx.x * 16 + (l & 15)) * 1024 + k32 * 32 + (l >> 4) * 8;
      float4 a = *(const float4*)p;
      float4 b = *(const float4*)(p + 4);
      alignas(16) unsigned o[4] = {pk2(a.x, a.y), pk2(a.z, a.w), pk2(b.x, b.y), pk2(b.z, b.w)};
      *(uint4*)(dst + (size_t)u * 8) = *(const uint4*)o;
    }
    return;
  }
  const int widx = blockIdx.y - 3;
  const float* W = widx == 0 ? Wq : (widx == 1 ? Wk : (widx == 2 ? Wv : Wo));
  bf16* dst = widx < 3 ? (Lw + (size_t)widx * 1048576) : Lwo;
  const int t = threadIdx.x, bx = blockIdx.x & 15, by = blockIdx.x >> 4;
#pragma unroll
  for (int i = 0; i < 4; ++i) {
    int u = t + i * 256, r = u >> 4, c4 = u & 15;
    *(float4*)&tf[r][c4 * 4] = *(const float4*)(W + (size_t)(by * 64 + r) * 1024 + bx * 64 + c4 * 4);
  }
  __syncthreads();
#pragma unroll
  for (int i = 0; i < 2; ++i) {
    int u = t + i * 256;
    int sub = u >> 6, l = u & 63;
    int n16l = sub >> 1, k32l = sub & 1;
    int nn = n16l * 16 + (l & 15);
    int kk = k32l * 32 + (l >> 4) * 8;
    alignas(16) unsigned o[4];
#pragma unroll
    for (int p = 0; p < 4; ++p) o[p] = pk2(tf[kk + 2 * p][nn], tf[kk + 2 * p + 1][nn]);
    size_t off = ((((size_t)(bx * 4 + n16l)) * 32 + (by * 2 + k32l)) * 64 + l) * 8;
    *(uint4*)(dst + off) = *(const uint4*)o;
  }
}

// ---------------- Fused QKV GEMM: 256x128 tile, BK=32, 3-deep prefetch ring ----------------
// R9 structure, prefetch deepened to distance 2: slab k's loads are issued 2
// iterations before use (~2 compute phases + 2 barrier rounds ~ covers the
// ~900cyc HBM miss latency that distance-1 [R6, null] could not).
// vmcnt: after issuing slab k+2 (3 loads/wave), outstanding = slabs k+1,k+2 = 6
// -> vmcnt(6) guarantees slab k landed. LDS 72KB -> still 2 blocks/CU.
__global__ __launch_bounds__(512, 4) void qkv_gemm(const bf16* __restrict__ Lw,
                                                   const bf16* __restrict__ Lx,
                                                   const float* __restrict__ bq,
                                                   const float* __restrict__ bk,
                                                   const float* __restrict__ bv,
                                                   bf16* __restrict__ Lq,
                                                   bf16* __restrict__ Lk,
                                                   bf16* __restrict__ Lv) {
  __shared__ alignas(16) bf16 At[3][8192];
  __shared__ alignas(16) bf16 Bt[3][4096];
  const int t = threadIdx.x, lane = t & 63, w = t >> 6;
  const int m16 = lane & 15, g4 = lane >> 4;
  const int bid = blockIdx.x;
  const int logical = (bid & 7) * 48 + (bid >> 3);
  const int third = logical >> 7;
  const int r = logical & 127;
  const int shift = third < 2 ? 5 : 3;
  const int mt = r >> shift, nt = r & ((1 << shift) - 1);
  const int wm = w >> 1, wn = w & 1;
  const bf16* Wb = Lw + (size_t)third * 1048576;
  const bf16* Xb = Lx + (size_t)third * (4096ull * 1024);
  const bf16* Asrc = third < 2 ? Wb : Xb;
  const bf16* Bsrc = third < 2 ? Xb : Wb;
  f32x4 acc[4][4] = {};

  // prologue: stage slabs 0,1 into bufs 0,1 (6 loads/wave total)
#pragma unroll
  for (int s0 = 0; s0 < 2; ++s0) {
#pragma unroll
    for (int ii = 0; ii < 3; ++ii) {
      int u = w * 3 + ii;
      if (u < 16)
        gload16(Asrc + (((size_t)(mt * 16 + u) * 32 + s0) * 64 + lane) * 8, (void*)&At[s0][u * 512]);
      else
        gload16(Bsrc + (((size_t)(nt * 8 + u - 16) * 32 + s0) * 64 + lane) * 8, (void*)&Bt[s0][(u - 16) * 512]);
    }
  }

  for (int k = 0; k < 32; ++k) {
    const int cb = k % 3;
    __builtin_amdgcn_s_barrier();            // A: buf (k+2)%3 free (its slab k-1 computed)
    __builtin_amdgcn_sched_barrier(0);
    if (k < 30) {
      const int nb = (k + 2) % 3;
#pragma unroll
      for (int ii = 0; ii < 3; ++ii) {
        int u = w * 3 + ii;
        if (u < 16)
          gload16(Asrc + (((size_t)(mt * 16 + u) * 32 + k + 2) * 64 + lane) * 8, (void*)&At[nb][u * 512]);
        else
          gload16(Bsrc + (((size_t)(nt * 8 + u - 16) * 32 + k + 2) * 64 + lane) * 8,
                  (void*)&Bt[nb][(u - 16) * 512]);
      }
      asm volatile("s_waitcnt vmcnt(6)" ::: "memory");  // slab k landed; k+1,k+2 in flight
    } else if (k == 30) {
      asm volatile("s_waitcnt vmcnt(3)" ::: "memory");  // slab 30 landed; 31 in flight
    } else {
      asm volatile("s_waitcnt vmcnt(0)" ::: "memory");
    }
    __builtin_amdgcn_sched_barrier(0);
    __builtin_amdgcn_s_barrier();            // B: every wave's slab-k loads landed
    __builtin_amdgcn_sched_barrier(0);

    bf16x8 afr[4], bfr[4];
#pragma unroll
    for (int i = 0; i < 4; ++i) afr[i] = *(const bf16x8*)&At[cb][(wm * 4 + i) * 512 + lane * 8];
#pragma unroll
    for (int j = 0; j < 4; ++j) bfr[j] = *(const bf16x8*)&Bt[cb][(wn * 4 + j) * 512 + lane * 8];
    __builtin_amdgcn_s_setprio(1);
#pragma unroll
    for (int i = 0; i < 4; ++i)
#pragma unroll
      for (int j = 0; j < 4; ++j) acc[i][j] = mfma16(afr[i], bfr[j], acc[i][j]);
    __builtin_amdgcn_s_setprio(0);
  }

  if (third < 2) {
    bf16* dst = third == 0 ? Lq : Lk;
    const float* bias = third == 0 ? bq : bk;
    const float sc = third == 0 ? QSCALE : 1.0f;
#pragma unroll
    for (int mi = 0; mi < 4; ++mi) {
      int doutb = mt * 256 + wm * 64 + mi * 16 + g4 * 4;
      float4 b4 = *(const float4*)(bias + doutb);
      int hh = doutb >> 6, d32 = (doutb & 63) >> 5;
      int lhi = (doutb & 31) >> 3, half = g4 & 1;
#pragma unroll
      for (int nj = 0; nj < 4; ++nj) {
        int seq = nt * 128 + wn * 64 + nj * 16 + m16;
        int bb2 = seq >> 11, s16w = (seq & 2047) >> 4;
        size_t off = ((((size_t)(bb2 * 128 + s16w)) * 16 + hh) * 2 + d32) * 512 + (m16 + 16 * lhi) * 8 + half * 4;
        uint2 pv;
        pv.x = pk2((acc[mi][nj][0] + b4.x) * sc, (acc[mi][nj][1] + b4.y) * sc);
        pv.y = pk2((acc[mi][nj][2] + b4.z) * sc, (acc[mi][nj][3] + b4.w) * sc);
        *(uint2*)(dst + off) = pv;
      }
    }
  } else {
#pragma unroll
    for (int nj = 0; nj < 4; ++nj) {
      int dout = nt * 128 + wn * 64 + nj * 16 + m16;
      float bvv = bv[dout];
      int hh = dout >> 6, dt = (dout & 63) >> 4;
#pragma unroll
      for (int mi = 0; mi < 4; ++mi) {
        int seqb = mt * 256 + wm * 64 + mi * 16 + g4 * 4;
        int b_ = seqb >> 11, kt = (seqb & 2047) >> 6, ks32 = (seqb & 63) >> 5;
        int lhi = (seqb & 31) >> 3, half = g4 & 1;
        size_t off = (((((size_t)(b_ * 32 + kt)) * 16 + hh) * 4 + dt) * 2 + ks32) * 512 + (m16 + 16 * lhi) * 8 + half * 4;
        uint2 pv;
        pv.x = pk2(acc[mi][nj][0] + bvv, acc[mi][nj][1] + bvv);
        pv.y = pk2(acc[mi][nj][2] + bvv, acc[mi][nj][3] + bvv);
        *(uint2*)(Lv + off) = pv;
      }
    }
  }
}

// ---------------- Flash attention: staged K/V (R9) + l-sum on the MFMA pipe ----------------
// lacc = mfma32(ones, bP[c], lacc): with A = all-ones, D[r][q] = sum_k P[k][q]
// (layout-independent). Replaces the 15-add VALU tree per chunk AND the final
// shfl_xor -- shifts work from the hot pipe (VALU 50%) to the idle one (MFMA 28%).
__global__ __launch_bounds__(512, 4) void flash(const bf16* __restrict__ Lq,
                                                const bf16* __restrict__ Lk,
                                                const bf16* __restrict__ Lv,
                                                bf16* __restrict__ Lab) {
  __shared__ alignas(16) unsigned char smem[65536];
  bf16* const Kb = (bf16*)smem;
  bf16* const Vb = (bf16*)(smem + 32768);

  const int t = threadIdx.x, lane = t & 63, w = t >> 6;
  const int l31 = lane & 31, m16 = lane & 15, hi = lane >> 5, b4 = (lane >> 4) & 1;
  const int qw = w >> 1, g = w & 1, wg = w >> 1;
  const int bid = blockIdx.x;
  const int logical = ((bid & 7) << 6) | (bid >> 3);
  const int qt = logical & 15, h = (logical >> 4) & 15, b = logical >> 8;

  alignas(16) const unsigned onesw[4] = {0x3F803F80u, 0x3F803F80u, 0x3F803F80u, 0x3F803F80u};
  const bf16x8 onesf = *(const bf16x8*)onesw;  // bf16 1.0 x8

  bf16x8 qf[4];
  {
    const int sQ = b * 128 + qt * 8 + qw * 2 + b4;
#pragma unroll
    for (int ks = 0; ks < 4; ++ks) {
      const int d32 = ks >> 1, g4q = (ks & 1) * 2 + hi;
      qf[ks] = *(const bf16x8*)(Lq + (((size_t)sQ * 16 + h) * 2 + d32) * 512 + (m16 + 16 * g4q) * 8);
    }
  }

  const int ss = wg >> 1, sd = wg & 1;
#pragma unroll
  for (int u = 0; u < 2; ++u) {
    const bf16* gk = Lk + ((((size_t)(b * 128 + g * 64 + u * 2 + ss)) * 16 + h) * 2 + sd) * 512 + lane * 8;
    gload16(gk, (void*)(Kb + (g * 2 + 0) * 4096 + u * 2048 + wg * 512));
    const bf16* gv = Lv + (((((size_t)(b * 32 + g * 16)) * 16 + h) * 4 + wg) * 2 + u) * 512 + lane * 8;
    gload16(gv, (void*)(Vb + (g * 2 + 0) * 4096 + u * 2048 + wg * 512));
  }

  f32x16 lacc = {};
  f32x16 oacc[2] = {};
  __syncthreads();

  for (int it = 0; it < 16; ++it) {
    const int cur = it & 1;
    const bf16* const Klb = Kb + (g * 2 + cur) * 4096;
    const bf16* const Vlb = Vb + (g * 2 + cur) * 4096;
    if (it < 15) {
      const int nb = cur ^ 1;
#pragma unroll
      for (int u = 0; u < 2; ++u) {
        const int kc = (it + 1) * 2 + u;
        const bf16* gk = Lk + ((((size_t)(b * 128 + g * 64 + kc * 2 + ss)) * 16 + h) * 2 + sd) * 512 + lane * 8;
        gload16(gk, (void*)(Kb + (g * 2 + nb) * 4096 + u * 2048 + wg * 512));
        const bf16* gv = Lv + (((((size_t)(b * 32 + g * 16 + (kc >> 1))) * 16 + h) * 4 + wg) * 2 + (kc & 1)) * 512 + lane * 8;
        gload16(gv, (void*)(Vb + (g * 2 + nb) * 4096 + u * 2048 + wg * 512));
      }
    }

#pragma unroll
    for (int u = 0; u < 2; ++u) {
      const bf16* const Kl = Klb + u * 2048;
      const bf16* const Vl = Vlb + u * 2048;

      f32x16 s = {};
      __builtin_amdgcn_s_setprio(1);
#pragma unroll
      for (int ks = 0; ks < 4; ++ks) {
        const int d32 = ks >> 1, g4k = (ks & 1) * 2 + hi;
        bf16x8 kf = *(const bf16x8*)&Kl[((b4 * 2 + d32) * 64 + m16 + 16 * g4k) * 8];
        s = mfma32(kf, qf[ks], s);
      }
      __builtin_amdgcn_s_setprio(0);

      float e[16];
#pragma unroll
      for (int r = 0; r < 16; ++r) e[r] = fexp2(s[r]);
      bf16x8 bP[2];
#pragma unroll
      for (int c = 0; c < 2; ++c) {
        unsigned P0 = pk2(e[8 * c + 0], e[8 * c + 1]);
        unsigned P1 = pk2(e[8 * c + 2], e[8 * c + 3]);
        unsigned P2 = pk2(e[8 * c + 4], e[8 * c + 5]);
        unsigned P3 = pk2(e[8 * c + 6], e[8 * c + 7]);
        plswap(P0, P2);
        plswap(P1, P3);
        alignas(16) unsigned pw[4] = {P0, P1, P2, P3};
        bP[c] = *(const bf16x8*)pw;
      }

      __builtin_amdgcn_s_setprio(1);
#pragma unroll
      for (int dtile = 0; dtile < 2; ++dtile) {
        const int dt = dtile * 2 + b4;
#pragma unroll
        for (int c = 0; c < 2; ++c) {
          bf16x8 av = *(const bf16x8*)&Vl[(dt * 64 + m16 + 16 * (2 * c + hi)) * 8];
          oacc[dtile] = mfma32(av, bP[c], oacc[dtile]);
        }
      }
      // l-sum on the matrix pipe: every row of lacc accumulates sum_k P[k][q=l31]
      lacc = mfma32(onesf, bP[0], lacc);
      lacc = mfma32(onesf, bP[1], lacc);
      __builtin_amdgcn_s_setprio(0);
    }
    __syncthreads();
  }

  const float lv = lacc[0];  // per-lane: l for q = l31 over this group's 1024 keys

  float* const Os = (float*)smem;              // [8][16][64]
  float* const Ls = (float*)(smem + 32768);    // [4][32]
  if (g == 1) {
#pragma unroll
    for (int dtile = 0; dtile < 2; ++dtile)
#pragma unroll
      for (int r = 0; r < 16; ++r)
        Os[((qw * 2 + dtile) * 16 + r) * 64 + lane] = oacc[dtile][r];
    if (hi == 0) Ls[qw * 32 + l31] = lv;
  }
  __syncthreads();
  if (g == 0) {
    const float inv = 1.f / (lv + Ls[qw * 32 + l31]);
    const int sQ = b * 128 + qt * 8 + qw * 2 + b4;
#pragma unroll
    for (int dtile = 0; dtile < 2; ++dtile) {
      const int k32 = h * 2 + dtile;
#pragma unroll
      for (int j = 0; j < 8; ++j) {
        const int r = 2 * j;
        float o0 = oacc[dtile][r] + Os[((qw * 2 + dtile) * 16 + r) * 64 + lane];
        float o1 = oacc[dtile][r + 1] + Os[((qw * 2 + dtile) * 16 + r + 1) * 64 + lane];
        unsigned pv = pk2(o0 * inv, o1 * inv);
        size_t off = ((size_t)sQ * 32 + k32) * 512 + (m16 + 16 * (r >> 2)) * 8 + 4 * hi + (r & 3);
        *(unsigned*)(Lab + off) = pv;
      }
    }
  }
}

// ---------------- Final GEMM: dbuf + counted vmcnt, XCD swizzle ----------------
__global__ __launch_bounds__(256) void out_gemm(const bf16* __restrict__ Lab,
                                                const bf16* __restrict__ Lwo,
                                                const float* __restrict__ bo,
                                                float* __restrict__ out) {
  __shared__ alignas(16) bf16 Al[2][8192];
  __shared__ alignas(16) bf16 Bl[2][4096];
  const int t = threadIdx.x, lane = t & 63, w = t >> 6;
  const int m16 = lane & 15, g4 = lane >> 4;
  const int bid = blockIdx.y * 16 + blockIdx.x;
  const int logical = (bid & 7) * 64 + (bid >> 3);
  const int nt = logical & 15, mt = logical >> 4;
  const int wm = w >> 1, wn = w & 1;
  f32x4 acc[4][2] = {};

#pragma unroll
  for (int ii = 0; ii < 4; ++ii) {
    int s = w * 4 + ii;
    gload16(Lab + (((size_t)(mt * 8 + (s >> 1))) * 32 + (s & 1)) * 512 + lane * 8, (void*)&Al[0][s * 512]);
  }
#pragma unroll
  for (int ii = 0; ii < 2; ++ii) {
    int s = w * 2 + ii;
    gload16(Lwo + (((size_t)(nt * 4 + (s >> 1))) * 32 + (s & 1)) * 512 + lane * 8, (void*)&Bl[0][s * 512]);
  }

  int cur = 0;
  for (int slab = 0; slab < 16; ++slab) {
    __builtin_amdgcn_s_barrier();
    __builtin_amdgcn_sched_barrier(0);
    if (slab < 15) {
      const int nb = cur ^ 1, ns = slab + 1;
#pragma unroll
      for (int ii = 0; ii < 4; ++ii) {
        int s = w * 4 + ii;
        gload16(Lab + (((size_t)(mt * 8 + (s >> 1))) * 32 + ns * 2 + (s & 1)) * 512 + lane * 8,
                (void*)&Al[nb][s * 512]);
      }
#pragma unroll
      for (int ii = 0; ii < 2; ++ii) {
        int s = w * 2 + ii;
        gload16(Lwo + (((size_t)(nt * 4 + (s >> 1))) * 32 + ns * 2 + (s & 1)) * 512 + lane * 8,
                (void*)&Bl[nb][s * 512]);
      }
      asm volatile("s_waitcnt vmcnt(6)" ::: "memory");
    } else {
      asm volatile("s_waitcnt vmcnt(0)" ::: "memory");
    }
    __builtin_amdgcn_sched_barrier(0);
    __builtin_amdgcn_s_barrier();
    __builtin_amdgcn_sched_barrier(0);
#pragma unroll
    for (int c = 0; c < 2; ++c) {
      bf16x8 aA[4], bW[2];
#pragma unroll
      for (int i = 0; i < 4; ++i) aA[i] = *(const bf16x8*)&Al[cur][((wm * 4 + i) * 2 + c) * 512 + lane * 8];
#pragma unroll
      for (int j = 0; j < 2; ++j) bW[j] = *(const bf16x8*)&Bl[cur][((wn * 2 + j) * 2 + c) * 512 + lane * 8];
      __builtin_amdgcn_s_setprio(1);
#pragma unroll
      for (int i = 0; i < 4; ++i)
#pragma unroll
        for (int j = 0; j < 2; ++j) acc[i][j] = mfma16(aA[i], bW[j], acc[i][j]);
      __builtin_amdgcn_s_setprio(0);
    }
    cur ^= 1;
  }
#pragma unroll
  for (int j = 0; j < 2; ++j) {
    int n = nt * 64 + wn * 32 + j * 16 + m16;
    float bb = bo[n];
#pragma unroll
    for (int i = 0; i < 4; ++i) {
      int seqb = mt * 128 + wm * 64 + i * 16 + g4 * 4;
#pragma unroll
      for (int r = 0; r < 4; ++r) out[(size_t)(seqb + r) * 1024 + n] = acc[i][j][r] + bb;
    }
  }
}

extern "C" void kernel_launch(void* const* d_in, const int* in_sizes, int n_in,
                              void* d_out, int out_size, void* d_ws, size_t ws_size,
                              hipStream_t stream) {
  const float* query = (const float*)d_in[0];
  const float* key   = (const float*)d_in[1];
  const float* value = (const float*)d_in[2];
  const float* Wq = (const float*)d_in[3];
  const float* bq = (const float*)d_in[4];
  const float* Wk = (const float*)d_in[5];
  const float* bk = (const float*)d_in[6];
  const float* Wv = (const float*)d_in[7];
  const float* bv = (const float*)d_in[8];
  const float* Wo = (const float*)d_in[9];
  const float* bo = (const float*)d_in[10];
  float* out = (float*)d_out;

  bf16* Lw  = (bf16*)d_ws;
  bf16* Lwo = Lw + 3ull * 1048576;
  bf16* Lx  = Lwo + 1048576;
  bf16* Lq  = Lx + 3ull * 4194304;
  bf16* Lk  = Lq + 4194304;
  bf16* Lv  = Lk + 4194304;
  bf16* Lab = Lv + 4194304;

  cast_all<<<dim3(256, 7), 256, 0, stream>>>(query, key, value, Wq, Wk, Wv, Wo, Lx, Lw, Lwo);
  qkv_gemm<<<384, 512, 0, stream>>>(Lw, Lx, bq, bk, bv, Lq, Lk, Lv);
  flash<<<512, 512, 0, stream>>>(Lq, Lk, Lv, Lab);
  out_gemm<<<dim3(16, 32), 256, 0, stream>>>(Lab, Lwo, bo, out);
}

// Round 14
// 210.022 us; speedup vs baseline: 1.5855x; 1.0045x over previous
//
#include <hip/hip_runtime.h>
#include <hip/hip_bf16.h>

using bf16 = __hip_bfloat16;
typedef __bf16 bf16x8 __attribute__((ext_vector_type(8)));
typedef __bf16 bf16x2v __attribute__((ext_vector_type(2)));
typedef float f32x4 __attribute__((ext_vector_type(4)));
typedef float f32x16 __attribute__((ext_vector_type(16)));

#define SEQ 2048
#define DM  1024
// 0.125 * log2(e): folded into Q so scores come out of MFMA in log2 domain.
#define QSCALE 0.18033688011112042f

__device__ __forceinline__ f32x4 mfma16(bf16x8 a, bf16x8 b, f32x4 c) {
  return __builtin_amdgcn_mfma_f32_16x16x32_bf16(a, b, c, 0, 0, 0);
}
__device__ __forceinline__ f32x16 mfma32(bf16x8 a, bf16x8 b, f32x16 c) {
  return __builtin_amdgcn_mfma_f32_32x32x16_bf16(a, b, c, 0, 0, 0);
}
__device__ __forceinline__ void gload16(const void* g, void* l) {
  __builtin_amdgcn_global_load_lds(
      (const __attribute__((address_space(1))) unsigned int*)g,
      (__attribute__((address_space(3))) unsigned int*)l, 16, 0, 0);
}
__device__ __forceinline__ unsigned short bfbits(float x) {
  bf16 h = __float2bfloat16(x);
  return *reinterpret_cast<unsigned short*>(&h);
}
__device__ __forceinline__ unsigned pk2(float a, float b) {
#if __has_builtin(__builtin_amdgcn_cvt_pk_bf16_f32)
  bf16x2v r = __builtin_amdgcn_cvt_pk_bf16_f32(a, b);
  return *reinterpret_cast<unsigned*>(&r);
#else
  return (unsigned)bfbits(a) | ((unsigned)bfbits(b) << 16);
#endif
}
__device__ __forceinline__ float fexp2(float x) {
#if __has_builtin(__builtin_amdgcn_exp2f)
  return __builtin_amdgcn_exp2f(x);
#else
  return exp2f(x);
#endif
}
// v_permlane32_swap_b32 a, b: a[l>=32] <- b[l-32]; b[l<32] <- a[l+32].
__device__ __forceinline__ void plswap(unsigned& a, unsigned& b) {
  asm("v_permlane32_swap_b32 %0, %1" : "+v"(a), "+v"(b));
}

// ---------------- Fused cast pass: X and W -> frag-tiled bf16 ----------------
__global__ __launch_bounds__(256) void cast_all(const float* __restrict__ q,
                                                const float* __restrict__ k,
                                                const float* __restrict__ v,
                                                const float* __restrict__ Wq,
                                                const float* __restrict__ Wk,
                                                const float* __restrict__ Wv,
                                                const float* __restrict__ Wo,
                                                bf16* __restrict__ Lx,
                                                bf16* __restrict__ Lw,
                                                bf16* __restrict__ Lwo) {
  __shared__ float tf[64][68];
  if (blockIdx.y < 3) {
    const float* src = blockIdx.y == 0 ? q : (blockIdx.y == 1 ? k : v);
    bf16* dst = Lx + (size_t)blockIdx.y * (4096ull * 1024) + (size_t)blockIdx.x * 16384;
#pragma unroll
    for (int i = 0; i < 8; ++i) {
      int u = threadIdx.x + i * 256;
      int k32 = u >> 6, l = u & 63;
      const float* p = src + (size_t)(blockIdx.x * 16 + (l & 15)) * 1024 + k32 * 32 + (l >> 4) * 8;
      float4 a = *(const float4*)p;
      float4 b = *(const float4*)(p + 4);
      alignas(16) unsigned o[4] = {pk2(a.x, a.y), pk2(a.z, a.w), pk2(b.x, b.y), pk2(b.z, b.w)};
      *(uint4*)(dst + (size_t)u * 8) = *(const uint4*)o;
    }
    return;
  }
  const int widx = blockIdx.y - 3;
  const float* W = widx == 0 ? Wq : (widx == 1 ? Wk : (widx == 2 ? Wv : Wo));
  bf16* dst = widx < 3 ? (Lw + (size_t)widx * 1048576) : Lwo;
  const int t = threadIdx.x, bx = blockIdx.x & 15, by = blockIdx.x >> 4;
#pragma unroll
  for (int i = 0; i < 4; ++i) {
    int u = t + i * 256, r = u >> 4, c4 = u & 15;
    *(float4*)&tf[r][c4 * 4] = *(const float4*)(W + (size_t)(by * 64 + r) * 1024 + bx * 64 + c4 * 4);
  }
  __syncthreads();
#pragma unroll
  for (int i = 0; i < 2; ++i) {
    int u = t + i * 256;
    int sub = u >> 6, l = u & 63;
    int n16l = sub >> 1, k32l = sub & 1;
    int nn = n16l * 16 + (l & 15);
    int kk = k32l * 32 + (l >> 4) * 8;
    alignas(16) unsigned o[4];
#pragma unroll
    for (int p = 0; p < 4; ++p) o[p] = pk2(tf[kk + 2 * p][nn], tf[kk + 2 * p + 1][nn]);
    size_t off = ((((size_t)(bx * 4 + n16l)) * 32 + (by * 2 + k32l)) * 64 + l) * 8;
    *(uint4*)(dst + off) = *(const uint4*)o;
  }
}

// ---------------- Fused QKV GEMM: 256x128 tile, BK=32, dbuf + counted vmcnt (R9) ----------------
__global__ __launch_bounds__(512, 4) void qkv_gemm(const bf16* __restrict__ Lw,
                                                   const bf16* __restrict__ Lx,
                                                   const float* __restrict__ bq,
                                                   const float* __restrict__ bk,
                                                   const float* __restrict__ bv,
                                                   bf16* __restrict__ Lq,
                                                   bf16* __restrict__ Lk,
                                                   bf16* __restrict__ Lv) {
  __shared__ alignas(16) bf16 At[2][8192];
  __shared__ alignas(16) bf16 Bt[2][4096];
  const int t = threadIdx.x, lane = t & 63, w = t >> 6;
  const int m16 = lane & 15, g4 = lane >> 4;
  const int bid = blockIdx.x;
  const int logical = (bid & 7) * 48 + (bid >> 3);
  const int third = logical >> 7;
  const int r = logical & 127;
  const int shift = third < 2 ? 5 : 3;
  const int mt = r >> shift, nt = r & ((1 << shift) - 1);
  const int wm = w >> 1, wn = w & 1;
  const bf16* Wb = Lw + (size_t)third * 1048576;
  const bf16* Xb = Lx + (size_t)third * (4096ull * 1024);
  const bf16* Asrc = third < 2 ? Wb : Xb;
  const bf16* Bsrc = third < 2 ? Xb : Wb;
  f32x4 acc[4][4] = {};

#pragma unroll
  for (int ii = 0; ii < 3; ++ii) {
    int u = w * 3 + ii;
    if (u < 16)
      gload16(Asrc + (((size_t)(mt * 16 + u) * 32 + 0) * 64 + lane) * 8, (void*)&At[0][u * 512]);
    else
      gload16(Bsrc + (((size_t)(nt * 8 + u - 16) * 32 + 0) * 64 + lane) * 8, (void*)&Bt[0][(u - 16) * 512]);
  }

  int cur = 0;
  for (int k = 0; k < 32; ++k) {
    __builtin_amdgcn_s_barrier();
    __builtin_amdgcn_sched_barrier(0);
    if (k < 31) {
      const int nb = cur ^ 1;
#pragma unroll
      for (int ii = 0; ii < 3; ++ii) {
        int u = w * 3 + ii;
        if (u < 16)
          gload16(Asrc + (((size_t)(mt * 16 + u) * 32 + k + 1) * 64 + lane) * 8, (void*)&At[nb][u * 512]);
        else
          gload16(Bsrc + (((size_t)(nt * 8 + u - 16) * 32 + k + 1) * 64 + lane) * 8,
                  (void*)&Bt[nb][(u - 16) * 512]);
      }
      asm volatile("s_waitcnt vmcnt(3)" ::: "memory");
    } else {
      asm volatile("s_waitcnt vmcnt(0)" ::: "memory");
    }
    __builtin_amdgcn_sched_barrier(0);
    __builtin_amdgcn_s_barrier();
    __builtin_amdgcn_sched_barrier(0);

    bf16x8 afr[4], bfr[4];
#pragma unroll
    for (int i = 0; i < 4; ++i) afr[i] = *(const bf16x8*)&At[cur][(wm * 4 + i) * 512 + lane * 8];
#pragma unroll
    for (int j = 0; j < 4; ++j) bfr[j] = *(const bf16x8*)&Bt[cur][(wn * 4 + j) * 512 + lane * 8];
    __builtin_amdgcn_s_setprio(1);
#pragma unroll
    for (int i = 0; i < 4; ++i)
#pragma unroll
      for (int j = 0; j < 4; ++j) acc[i][j] = mfma16(afr[i], bfr[j], acc[i][j]);
    __builtin_amdgcn_s_setprio(0);
    cur ^= 1;
  }

  if (third < 2) {
    bf16* dst = third == 0 ? Lq : Lk;
    const float* bias = third == 0 ? bq : bk;
    const float sc = third == 0 ? QSCALE : 1.0f;
#pragma unroll
    for (int mi = 0; mi < 4; ++mi) {
      int doutb = mt * 256 + wm * 64 + mi * 16 + g4 * 4;
      float4 b4 = *(const float4*)(bias + doutb);
      int hh = doutb >> 6, d32 = (doutb & 63) >> 5;
      int lhi = (doutb & 31) >> 3, half = g4 & 1;
#pragma unroll
      for (int nj = 0; nj < 4; ++nj) {
        int seq = nt * 128 + wn * 64 + nj * 16 + m16;
        int bb2 = seq >> 11, s16w = (seq & 2047) >> 4;
        size_t off = ((((size_t)(bb2 * 128 + s16w)) * 16 + hh) * 2 + d32) * 512 + (m16 + 16 * lhi) * 8 + half * 4;
        uint2 pv;
        pv.x = pk2((acc[mi][nj][0] + b4.x) * sc, (acc[mi][nj][1] + b4.y) * sc);
        pv.y = pk2((acc[mi][nj][2] + b4.z) * sc, (acc[mi][nj][3] + b4.w) * sc);
        *(uint2*)(dst + off) = pv;
      }
    }
  } else {
#pragma unroll
    for (int nj = 0; nj < 4; ++nj) {
      int dout = nt * 128 + wn * 64 + nj * 16 + m16;
      float bvv = bv[dout];
      int hh = dout >> 6, dt = (dout & 63) >> 4;
#pragma unroll
      for (int mi = 0; mi < 4; ++mi) {
        int seqb = mt * 256 + wm * 64 + mi * 16 + g4 * 4;
        int b_ = seqb >> 11, kt = (seqb & 2047) >> 6, ks32 = (seqb & 63) >> 5;
        int lhi = (seqb & 31) >> 3, half = g4 & 1;
        size_t off = (((((size_t)(b_ * 32 + kt)) * 16 + hh) * 4 + dt) * 2 + ks32) * 512 + (m16 + 16 * lhi) * 8 + half * 4;
        uint2 pv;
        pv.x = pk2(acc[mi][nj][0] + bvv, acc[mi][nj][1] + bvv);
        pv.y = pk2(acc[mi][nj][2] + bvv, acc[mi][nj][3] + bvv);
        *(uint2*)(Lv + off) = pv;
      }
    }
  }
}

// ---------------- Flash attention: staged K/V, 2-chunk within-wave pipeline ----------------
// Both 32-key chunks' QK^T are computed UP FRONT (8 MFMAs queued): softmax(s0)
// runs on VALU under QK(1)'s tail; PV(0) queues on MFMA under softmax(s1).
// Breaks the strictly serial QK->exp2->pack->PV chain that pinned dur at 47us
// while both pipes sat <50% (R13: pipe-shift moved counters, not time).
__global__ __launch_bounds__(512, 4) void flash(const bf16* __restrict__ Lq,
                                                const bf16* __restrict__ Lk,
                                                const bf16* __restrict__ Lv,
                                                bf16* __restrict__ Lab) {
  __shared__ alignas(16) unsigned char smem[65536];
  bf16* const Kb = (bf16*)smem;
  bf16* const Vb = (bf16*)(smem + 32768);

  const int t = threadIdx.x, lane = t & 63, w = t >> 6;
  const int l31 = lane & 31, m16 = lane & 15, hi = lane >> 5, b4 = (lane >> 4) & 1;
  const int qw = w >> 1, g = w & 1, wg = w >> 1;
  const int bid = blockIdx.x;
  const int logical = ((bid & 7) << 6) | (bid >> 3);
  const int qt = logical & 15, h = (logical >> 4) & 15, b = logical >> 8;

  bf16x8 qf[4];
  {
    const int sQ = b * 128 + qt * 8 + qw * 2 + b4;
#pragma unroll
    for (int ks = 0; ks < 4; ++ks) {
      const int d32 = ks >> 1, g4q = (ks & 1) * 2 + hi;
      qf[ks] = *(const bf16x8*)(Lq + (((size_t)sQ * 16 + h) * 2 + d32) * 512 + (m16 + 16 * g4q) * 8);
    }
  }

  const int ss = wg >> 1, sd = wg & 1;
#pragma unroll
  for (int u = 0; u < 2; ++u) {
    const bf16* gk = Lk + ((((size_t)(b * 128 + g * 64 + u * 2 + ss)) * 16 + h) * 2 + sd) * 512 + lane * 8;
    gload16(gk, (void*)(Kb + (g * 2 + 0) * 4096 + u * 2048 + wg * 512));
    const bf16* gv = Lv + (((((size_t)(b * 32 + g * 16)) * 16 + h) * 4 + wg) * 2 + u) * 512 + lane * 8;
    gload16(gv, (void*)(Vb + (g * 2 + 0) * 4096 + u * 2048 + wg * 512));
  }

  float lrow = 0.f;
  f32x16 oacc[2] = {};
  __syncthreads();

  for (int it = 0; it < 16; ++it) {
    const int cur = it & 1;
    const bf16* const Klb = Kb + (g * 2 + cur) * 4096;
    const bf16* const Vlb = Vb + (g * 2 + cur) * 4096;
    if (it < 15) {
      const int nb = cur ^ 1;
#pragma unroll
      for (int u = 0; u < 2; ++u) {
        const int kc = (it + 1) * 2 + u;
        const bf16* gk = Lk + ((((size_t)(b * 128 + g * 64 + kc * 2 + ss)) * 16 + h) * 2 + sd) * 512 + lane * 8;
        gload16(gk, (void*)(Kb + (g * 2 + nb) * 4096 + u * 2048 + wg * 512));
        const bf16* gv = Lv + (((((size_t)(b * 32 + g * 16 + (kc >> 1))) * 16 + h) * 4 + wg) * 2 + (kc & 1)) * 512 + lane * 8;
        gload16(gv, (void*)(Vb + (g * 2 + nb) * 4096 + u * 2048 + wg * 512));
      }
    }

    // ---- QK^T for BOTH 32-key chunks, queued back-to-back on the MFMA pipe ----
    f32x16 s0 = {}, s1 = {};
    __builtin_amdgcn_s_setprio(1);
#pragma unroll
    for (int ks = 0; ks < 4; ++ks) {
      const int d32 = ks >> 1, g4k = (ks & 1) * 2 + hi;
      bf16x8 kf = *(const bf16x8*)&Klb[((b4 * 2 + d32) * 64 + m16 + 16 * g4k) * 8];
      s0 = mfma32(kf, qf[ks], s0);
    }
#pragma unroll
    for (int ks = 0; ks < 4; ++ks) {
      const int d32 = ks >> 1, g4k = (ks & 1) * 2 + hi;
      bf16x8 kf = *(const bf16x8*)&Klb[2048 + ((b4 * 2 + d32) * 64 + m16 + 16 * g4k) * 8];
      s1 = mfma32(kf, qf[ks], s1);
    }
    __builtin_amdgcn_s_setprio(0);

    // ---- chunk 0: softmax (VALU, overlaps QK(1) tail) then PV (MFMA) ----
#pragma unroll
    for (int u = 0; u < 2; ++u) {
      const bf16* const Vl = Vlb + u * 2048;
      const f32x16& s = u == 0 ? s0 : s1;
      float e[16];
#pragma unroll
      for (int r = 0; r < 16; ++r) e[r] = fexp2(s[r]);
      {
        float a0 = e[0] + e[1], a1 = e[2] + e[3], a2 = e[4] + e[5], a3 = e[6] + e[7];
        float a4 = e[8] + e[9], a5 = e[10] + e[11], a6 = e[12] + e[13], a7 = e[14] + e[15];
        lrow += ((a0 + a1) + (a2 + a3)) + ((a4 + a5) + (a6 + a7));
      }
      bf16x8 bP[2];
#pragma unroll
      for (int c = 0; c < 2; ++c) {
        unsigned P0 = pk2(e[8 * c + 0], e[8 * c + 1]);
        unsigned P1 = pk2(e[8 * c + 2], e[8 * c + 3]);
        unsigned P2 = pk2(e[8 * c + 4], e[8 * c + 5]);
        unsigned P3 = pk2(e[8 * c + 6], e[8 * c + 7]);
        plswap(P0, P2);
        plswap(P1, P3);
        alignas(16) unsigned pw[4] = {P0, P1, P2, P3};
        bP[c] = *(const bf16x8*)pw;
      }
      __builtin_amdgcn_s_setprio(1);
#pragma unroll
      for (int dtile = 0; dtile < 2; ++dtile) {
        const int dt = dtile * 2 + b4;
#pragma unroll
        for (int c = 0; c < 2; ++c) {
          bf16x8 av = *(const bf16x8*)&Vl[(dt * 64 + m16 + 16 * (2 * c + hi)) * 8];
          oacc[dtile] = mfma32(av, bP[c], oacc[dtile]);
        }
      }
      __builtin_amdgcn_s_setprio(0);
    }
    __syncthreads();
  }

  lrow += __shfl_xor(lrow, 32);

  float* const Os = (float*)smem;              // [8][16][64]
  float* const Ls = (float*)(smem + 32768);    // [4][32]
  if (g == 1) {
#pragma unroll
    for (int dtile = 0; dtile < 2; ++dtile)
#pragma unroll
      for (int r = 0; r < 16; ++r)
        Os[((qw * 2 + dtile) * 16 + r) * 64 + lane] = oacc[dtile][r];
    if (hi == 0) Ls[qw * 32 + l31] = lrow;
  }
  __syncthreads();
  if (g == 0) {
    const float inv = 1.f / (lrow + Ls[qw * 32 + l31]);
    const int sQ = b * 128 + qt * 8 + qw * 2 + b4;
#pragma unroll
    for (int dtile = 0; dtile < 2; ++dtile) {
      const int k32 = h * 2 + dtile;
#pragma unroll
      for (int j = 0; j < 8; ++j) {
        const int r = 2 * j;
        float o0 = oacc[dtile][r] + Os[((qw * 2 + dtile) * 16 + r) * 64 + lane];
        float o1 = oacc[dtile][r + 1] + Os[((qw * 2 + dtile) * 16 + r + 1) * 64 + lane];
        unsigned pv = pk2(o0 * inv, o1 * inv);
        size_t off = ((size_t)sQ * 32 + k32) * 512 + (m16 + 16 * (r >> 2)) * 8 + 4 * hi + (r & 3);
        *(unsigned*)(Lab + off) = pv;
      }
    }
  }
}

// ---------------- Final GEMM: dbuf + counted vmcnt, XCD swizzle ----------------
__global__ __launch_bounds__(256) void out_gemm(const bf16* __restrict__ Lab,
                                                const bf16* __restrict__ Lwo,
                                                const float* __restrict__ bo,
                                                float* __restrict__ out) {
  __shared__ alignas(16) bf16 Al[2][8192];
  __shared__ alignas(16) bf16 Bl[2][4096];
  const int t = threadIdx.x, lane = t & 63, w = t >> 6;
  const int m16 = lane & 15, g4 = lane >> 4;
  const int bid = blockIdx.y * 16 + blockIdx.x;
  const int logical = (bid & 7) * 64 + (bid >> 3);
  const int nt = logical & 15, mt = logical >> 4;
  const int wm = w >> 1, wn = w & 1;
  f32x4 acc[4][2] = {};

#pragma unroll
  for (int ii = 0; ii < 4; ++ii) {
    int s = w * 4 + ii;
    gload16(Lab + (((size_t)(mt * 8 + (s >> 1))) * 32 + (s & 1)) * 512 + lane * 8, (void*)&Al[0][s * 512]);
  }
#pragma unroll
  for (int ii = 0; ii < 2; ++ii) {
    int s = w * 2 + ii;
    gload16(Lwo + (((size_t)(nt * 4 + (s >> 1))) * 32 + (s & 1)) * 512 + lane * 8, (void*)&Bl[0][s * 512]);
  }

  int cur = 0;
  for (int slab = 0; slab < 16; ++slab) {
    __builtin_amdgcn_s_barrier();
    __builtin_amdgcn_sched_barrier(0);
    if (slab < 15) {
      const int nb = cur ^ 1, ns = slab + 1;
#pragma unroll
      for (int ii = 0; ii < 4; ++ii) {
        int s = w * 4 + ii;
        gload16(Lab + (((size_t)(mt * 8 + (s >> 1))) * 32 + ns * 2 + (s & 1)) * 512 + lane * 8,
                (void*)&Al[nb][s * 512]);
      }
#pragma unroll
      for (int ii = 0; ii < 2; ++ii) {
        int s = w * 2 + ii;
        gload16(Lwo + (((size_t)(nt * 4 + (s >> 1))) * 32 + ns * 2 + (s & 1)) * 512 + lane * 8,
                (void*)&Bl[nb][s * 512]);
      }
      asm volatile("s_waitcnt vmcnt(6)" ::: "memory");
    } else {
      asm volatile("s_waitcnt vmcnt(0)" ::: "memory");
    }
    __builtin_amdgcn_sched_barrier(0);
    __builtin_amdgcn_s_barrier();
    __builtin_amdgcn_sched_barrier(0);
#pragma unroll
    for (int c = 0; c < 2; ++c) {
      bf16x8 aA[4], bW[2];
#pragma unroll
      for (int i = 0; i < 4; ++i) aA[i] = *(const bf16x8*)&Al[cur][((wm * 4 + i) * 2 + c) * 512 + lane * 8];
#pragma unroll
      for (int j = 0; j < 2; ++j) bW[j] = *(const bf16x8*)&Bl[cur][((wn * 2 + j) * 2 + c) * 512 + lane * 8];
      __builtin_amdgcn_s_setprio(1);
#pragma unroll
      for (int i = 0; i < 4; ++i)
#pragma unroll
        for (int j = 0; j < 2; ++j) acc[i][j] = mfma16(aA[i], bW[j], acc[i][j]);
      __builtin_amdgcn_s_setprio(0);
    }
    cur ^= 1;
  }
#pragma unroll
  for (int j = 0; j < 2; ++j) {
    int n = nt * 64 + wn * 32 + j * 16 + m16;
    float bb = bo[n];
#pragma unroll
    for (int i = 0; i < 4; ++i) {
      int seqb = mt * 128 + wm * 64 + i * 16 + g4 * 4;
#pragma unroll
      for (int r = 0; r < 4; ++r) out[(size_t)(seqb + r) * 1024 + n] = acc[i][j][r] + bb;
    }
  }
}

extern "C" void kernel_launch(void* const* d_in, const int* in_sizes, int n_in,
                              void* d_out, int out_size, void* d_ws, size_t ws_size,
                              hipStream_t stream) {
  const float* query = (const float*)d_in[0];
  const float* key   = (const float*)d_in[1];
  const float* value = (const float*)d_in[2];
  const float* Wq = (const float*)d_in[3];
  const float* bq = (const float*)d_in[4];
  const float* Wk = (const float*)d_in[5];
  const float* bk = (const float*)d_in[6];
  const float* Wv = (const float*)d_in[7];
  const float* bv = (const float*)d_in[8];
  const float* Wo = (const float*)d_in[9];
  const float* bo = (const float*)d_in[10];
  float* out = (float*)d_out;

  bf16* Lw  = (bf16*)d_ws;
  bf16* Lwo = Lw + 3ull * 1048576;
  bf16* Lx  = Lwo + 1048576;
  bf16* Lq  = Lx + 3ull * 4194304;
  bf16* Lk  = Lq + 4194304;
  bf16* Lv  = Lk + 4194304;
  bf16* Lab = Lv + 4194304;

  cast_all<<<dim3(256, 7), 256, 0, stream>>>(query, key, value, Wq, Wk, Wv, Wo, Lx, Lw, Lwo);
  qkv_gemm<<<384, 512, 0, stream>>>(Lw, Lx, bq, bk, bv, Lq, Lk, Lv);
  flash<<<512, 512, 0, stream>>>(Lq, Lk, Lv, Lab);
  out_gemm<<<dim3(16, 32), 256, 0, stream>>>(Lab, Lwo, bo, out);
}

// Round 15
// 206.100 us; speedup vs baseline: 1.6157x; 1.0190x over previous
//
#include <hip/hip_runtime.h>
#include <hip/hip_bf16.h>

using bf16 = __hip_bfloat16;
typedef __bf16 bf16x8 __attribute__((ext_vector_type(8)));
typedef __bf16 bf16x2v __attribute__((ext_vector_type(2)));
typedef float f32x4 __attribute__((ext_vector_type(4)));
typedef float f32x16 __attribute__((ext_vector_type(16)));

#define SEQ 2048
#define DM  1024
// 0.125 * log2(e): folded into Q so scores come out of MFMA in log2 domain.
#define QSCALE 0.18033688011112042f

__device__ __forceinline__ f32x4 mfma16(bf16x8 a, bf16x8 b, f32x4 c) {
  return __builtin_amdgcn_mfma_f32_16x16x32_bf16(a, b, c, 0, 0, 0);
}
__device__ __forceinline__ f32x16 mfma32(bf16x8 a, bf16x8 b, f32x16 c) {
  return __builtin_amdgcn_mfma_f32_32x32x16_bf16(a, b, c, 0, 0, 0);
}
__device__ __forceinline__ void gload16(const void* g, void* l) {
  __builtin_amdgcn_global_load_lds(
      (const __attribute__((address_space(1))) unsigned int*)g,
      (__attribute__((address_space(3))) unsigned int*)l, 16, 0, 0);
}
__device__ __forceinline__ unsigned short bfbits(float x) {
  bf16 h = __float2bfloat16(x);
  return *reinterpret_cast<unsigned short*>(&h);
}
__device__ __forceinline__ unsigned pk2(float a, float b) {
#if __has_builtin(__builtin_amdgcn_cvt_pk_bf16_f32)
  bf16x2v r = __builtin_amdgcn_cvt_pk_bf16_f32(a, b);
  return *reinterpret_cast<unsigned*>(&r);
#else
  return (unsigned)bfbits(a) | ((unsigned)bfbits(b) << 16);
#endif
}
__device__ __forceinline__ float fexp2(float x) {
#if __has_builtin(__builtin_amdgcn_exp2f)
  return __builtin_amdgcn_exp2f(x);
#else
  return exp2f(x);
#endif
}
// v_permlane32_swap_b32 a, b: a[l>=32] <- b[l-32]; b[l<32] <- a[l+32].
__device__ __forceinline__ void plswap(unsigned& a, unsigned& b) {
  asm("v_permlane32_swap_b32 %0, %1" : "+v"(a), "+v"(b));
}

// ---------------- Fused cast pass: X and W -> frag-tiled bf16 ----------------
// X-pass rewritten with an LDS transpose stage: phase 1 reads CONTIGUOUS
// float4s (fully coalesced, 128B/quarter-wave) instead of the old 64x discrete
// 32B segments per wave; phase 2 gathers the frag-tiled output from LDS
// (row stride 1032 bf16 -> 2-way bank aliasing, free) with coalesced stores.
__global__ __launch_bounds__(256) void cast_all(const float* __restrict__ q,
                                                const float* __restrict__ k,
                                                const float* __restrict__ v,
                                                const float* __restrict__ Wq,
                                                const float* __restrict__ Wk,
                                                const float* __restrict__ Wv,
                                                const float* __restrict__ Wo,
                                                bf16* __restrict__ Lx,
                                                bf16* __restrict__ Lw,
                                                bf16* __restrict__ Lwo) {
  __shared__ alignas(16) unsigned char sm[33024];
  const int t = threadIdx.x;
  if (blockIdx.y < 3) {
    const float* src = blockIdx.y == 0 ? q : (blockIdx.y == 1 ? k : v);
    const float* base = src + (size_t)blockIdx.x * 16 * 1024;
    bf16* dst = Lx + (size_t)blockIdx.y * (4096ull * 1024) + (size_t)blockIdx.x * 16384;
    bf16* const xs = (bf16*)sm;  // [16 rows][1032] bf16 (pad 8 -> 2-way banks)
    // phase 1: coalesced float4 loads, convert, LDS store
#pragma unroll
    for (int i = 0; i < 16; ++i) {
      int u = t + i * 256;            // float4 index; row = u>>8, col4 = u&255
      int row = u >> 8, c4 = u & 255;
      float4 a = *(const float4*)(base + (size_t)row * 1024 + c4 * 4);
      uint2 o;
      o.x = pk2(a.x, a.y);
      o.y = pk2(a.z, a.w);
      *(uint2*)&xs[row * 1032 + c4 * 4] = o;
    }
    __syncthreads();
    // phase 2: frag-tiled gather (16B-aligned LDS reads) + coalesced stores
#pragma unroll
    for (int i = 0; i < 8; ++i) {
      int u = t + i * 256;
      int k32 = u >> 6, l = u & 63;
      const bf16* p = &xs[(l & 15) * 1032 + k32 * 32 + (l >> 4) * 8];
      *(uint4*)(dst + (size_t)u * 8) = *(const uint4*)p;
    }
    return;
  }
  const int widx = blockIdx.y - 3;
  const float* W = widx == 0 ? Wq : (widx == 1 ? Wk : (widx == 2 ? Wv : Wo));
  bf16* dst = widx < 3 ? (Lw + (size_t)widx * 1048576) : Lwo;
  float* const tf = (float*)sm;  // [64][68]
  const int bx = blockIdx.x & 15, by = blockIdx.x >> 4;
#pragma unroll
  for (int i = 0; i < 4; ++i) {
    int u = t + i * 256, r = u >> 4, c4 = u & 15;
    *(float4*)&tf[r * 68 + c4 * 4] = *(const float4*)(W + (size_t)(by * 64 + r) * 1024 + bx * 64 + c4 * 4);
  }
  __syncthreads();
#pragma unroll
  for (int i = 0; i < 2; ++i) {
    int u = t + i * 256;
    int sub = u >> 6, l = u & 63;
    int n16l = sub >> 1, k32l = sub & 1;
    int nn = n16l * 16 + (l & 15);
    int kk = k32l * 32 + (l >> 4) * 8;
    alignas(16) unsigned o[4];
#pragma unroll
    for (int p = 0; p < 4; ++p) o[p] = pk2(tf[(kk + 2 * p) * 68 + nn], tf[(kk + 2 * p + 1) * 68 + nn]);
    size_t off = ((((size_t)(bx * 4 + n16l)) * 32 + (by * 2 + k32l)) * 64 + l) * 8;
    *(uint4*)(dst + off) = *(const uint4*)o;
  }
}

// ---------------- Fused QKV GEMM: 256x128 tile, BK=32, dbuf + counted vmcnt (R9) ----------------
__global__ __launch_bounds__(512, 4) void qkv_gemm(const bf16* __restrict__ Lw,
                                                   const bf16* __restrict__ Lx,
                                                   const float* __restrict__ bq,
                                                   const float* __restrict__ bk,
                                                   const float* __restrict__ bv,
                                                   bf16* __restrict__ Lq,
                                                   bf16* __restrict__ Lk,
                                                   bf16* __restrict__ Lv) {
  __shared__ alignas(16) bf16 At[2][8192];
  __shared__ alignas(16) bf16 Bt[2][4096];
  const int t = threadIdx.x, lane = t & 63, w = t >> 6;
  const int m16 = lane & 15, g4 = lane >> 4;
  const int bid = blockIdx.x;
  const int logical = (bid & 7) * 48 + (bid >> 3);
  const int third = logical >> 7;
  const int r = logical & 127;
  const int shift = third < 2 ? 5 : 3;
  const int mt = r >> shift, nt = r & ((1 << shift) - 1);
  const int wm = w >> 1, wn = w & 1;
  const bf16* Wb = Lw + (size_t)third * 1048576;
  const bf16* Xb = Lx + (size_t)third * (4096ull * 1024);
  const bf16* Asrc = third < 2 ? Wb : Xb;
  const bf16* Bsrc = third < 2 ? Xb : Wb;
  f32x4 acc[4][4] = {};

#pragma unroll
  for (int ii = 0; ii < 3; ++ii) {
    int u = w * 3 + ii;
    if (u < 16)
      gload16(Asrc + (((size_t)(mt * 16 + u) * 32 + 0) * 64 + lane) * 8, (void*)&At[0][u * 512]);
    else
      gload16(Bsrc + (((size_t)(nt * 8 + u - 16) * 32 + 0) * 64 + lane) * 8, (void*)&Bt[0][(u - 16) * 512]);
  }

  int cur = 0;
  for (int k = 0; k < 32; ++k) {
    __builtin_amdgcn_s_barrier();
    __builtin_amdgcn_sched_barrier(0);
    if (k < 31) {
      const int nb = cur ^ 1;
#pragma unroll
      for (int ii = 0; ii < 3; ++ii) {
        int u = w * 3 + ii;
        if (u < 16)
          gload16(Asrc + (((size_t)(mt * 16 + u) * 32 + k + 1) * 64 + lane) * 8, (void*)&At[nb][u * 512]);
        else
          gload16(Bsrc + (((size_t)(nt * 8 + u - 16) * 32 + k + 1) * 64 + lane) * 8,
                  (void*)&Bt[nb][(u - 16) * 512]);
      }
      asm volatile("s_waitcnt vmcnt(3)" ::: "memory");
    } else {
      asm volatile("s_waitcnt vmcnt(0)" ::: "memory");
    }
    __builtin_amdgcn_sched_barrier(0);
    __builtin_amdgcn_s_barrier();
    __builtin_amdgcn_sched_barrier(0);

    bf16x8 afr[4], bfr[4];
#pragma unroll
    for (int i = 0; i < 4; ++i) afr[i] = *(const bf16x8*)&At[cur][(wm * 4 + i) * 512 + lane * 8];
#pragma unroll
    for (int j = 0; j < 4; ++j) bfr[j] = *(const bf16x8*)&Bt[cur][(wn * 4 + j) * 512 + lane * 8];
    __builtin_amdgcn_s_setprio(1);
#pragma unroll
    for (int i = 0; i < 4; ++i)
#pragma unroll
      for (int j = 0; j < 4; ++j) acc[i][j] = mfma16(afr[i], bfr[j], acc[i][j]);
    __builtin_amdgcn_s_setprio(0);
    cur ^= 1;
  }

  if (third < 2) {
    bf16* dst = third == 0 ? Lq : Lk;
    const float* bias = third == 0 ? bq : bk;
    const float sc = third == 0 ? QSCALE : 1.0f;
#pragma unroll
    for (int mi = 0; mi < 4; ++mi) {
      int doutb = mt * 256 + wm * 64 + mi * 16 + g4 * 4;
      float4 b4 = *(const float4*)(bias + doutb);
      int hh = doutb >> 6, d32 = (doutb & 63) >> 5;
      int lhi = (doutb & 31) >> 3, half = g4 & 1;
#pragma unroll
      for (int nj = 0; nj < 4; ++nj) {
        int seq = nt * 128 + wn * 64 + nj * 16 + m16;
        int bb2 = seq >> 11, s16w = (seq & 2047) >> 4;
        size_t off = ((((size_t)(bb2 * 128 + s16w)) * 16 + hh) * 2 + d32) * 512 + (m16 + 16 * lhi) * 8 + half * 4;
        uint2 pv;
        pv.x = pk2((acc[mi][nj][0] + b4.x) * sc, (acc[mi][nj][1] + b4.y) * sc);
        pv.y = pk2((acc[mi][nj][2] + b4.z) * sc, (acc[mi][nj][3] + b4.w) * sc);
        *(uint2*)(dst + off) = pv;
      }
    }
  } else {
#pragma unroll
    for (int nj = 0; nj < 4; ++nj) {
      int dout = nt * 128 + wn * 64 + nj * 16 + m16;
      float bvv = bv[dout];
      int hh = dout >> 6, dt = (dout & 63) >> 4;
#pragma unroll
      for (int mi = 0; mi < 4; ++mi) {
        int seqb = mt * 256 + wm * 64 + mi * 16 + g4 * 4;
        int b_ = seqb >> 11, kt = (seqb & 2047) >> 6, ks32 = (seqb & 63) >> 5;
        int lhi = (seqb & 31) >> 3, half = g4 & 1;
        size_t off = (((((size_t)(b_ * 32 + kt)) * 16 + hh) * 4 + dt) * 2 + ks32) * 512 + (m16 + 16 * lhi) * 8 + half * 4;
        uint2 pv;
        pv.x = pk2(acc[mi][nj][0] + bvv, acc[mi][nj][1] + bvv);
        pv.y = pk2(acc[mi][nj][2] + bvv, acc[mi][nj][3] + bvv);
        *(uint2*)(Lv + off) = pv;
      }
    }
  }
}

// ---------------- Flash attention: staged K/V, 2-chunk within-wave pipeline (R14) ----------------
__global__ __launch_bounds__(512, 4) void flash(const bf16* __restrict__ Lq,
                                                const bf16* __restrict__ Lk,
                                                const bf16* __restrict__ Lv,
                                                bf16* __restrict__ Lab) {
  __shared__ alignas(16) unsigned char smem[65536];
  bf16* const Kb = (bf16*)smem;
  bf16* const Vb = (bf16*)(smem + 32768);

  const int t = threadIdx.x, lane = t & 63, w = t >> 6;
  const int l31 = lane & 31, m16 = lane & 15, hi = lane >> 5, b4 = (lane >> 4) & 1;
  const int qw = w >> 1, g = w & 1, wg = w >> 1;
  const int bid = blockIdx.x;
  const int logical = ((bid & 7) << 6) | (bid >> 3);
  const int qt = logical & 15, h = (logical >> 4) & 15, b = logical >> 8;

  bf16x8 qf[4];
  {
    const int sQ = b * 128 + qt * 8 + qw * 2 + b4;
#pragma unroll
    for (int ks = 0; ks < 4; ++ks) {
      const int d32 = ks >> 1, g4q = (ks & 1) * 2 + hi;
      qf[ks] = *(const bf16x8*)(Lq + (((size_t)sQ * 16 + h) * 2 + d32) * 512 + (m16 + 16 * g4q) * 8);
    }
  }

  const int ss = wg >> 1, sd = wg & 1;
#pragma unroll
  for (int u = 0; u < 2; ++u) {
    const bf16* gk = Lk + ((((size_t)(b * 128 + g * 64 + u * 2 + ss)) * 16 + h) * 2 + sd) * 512 + lane * 8;
    gload16(gk, (void*)(Kb + (g * 2 + 0) * 4096 + u * 2048 + wg * 512));
    const bf16* gv = Lv + (((((size_t)(b * 32 + g * 16)) * 16 + h) * 4 + wg) * 2 + u) * 512 + lane * 8;
    gload16(gv, (void*)(Vb + (g * 2 + 0) * 4096 + u * 2048 + wg * 512));
  }

  float lrow = 0.f;
  f32x16 oacc[2] = {};
  __syncthreads();

  for (int it = 0; it < 16; ++it) {
    const int cur = it & 1;
    const bf16* const Klb = Kb + (g * 2 + cur) * 4096;
    const bf16* const Vlb = Vb + (g * 2 + cur) * 4096;
    if (it < 15) {
      const int nb = cur ^ 1;
#pragma unroll
      for (int u = 0; u < 2; ++u) {
        const int kc = (it + 1) * 2 + u;
        const bf16* gk = Lk + ((((size_t)(b * 128 + g * 64 + kc * 2 + ss)) * 16 + h) * 2 + sd) * 512 + lane * 8;
        gload16(gk, (void*)(Kb + (g * 2 + nb) * 4096 + u * 2048 + wg * 512));
        const bf16* gv = Lv + (((((size_t)(b * 32 + g * 16 + (kc >> 1))) * 16 + h) * 4 + wg) * 2 + (kc & 1)) * 512 + lane * 8;
        gload16(gv, (void*)(Vb + (g * 2 + nb) * 4096 + u * 2048 + wg * 512));
      }
    }

    // QK^T for BOTH 32-key chunks, queued back-to-back on the MFMA pipe
    f32x16 s0 = {}, s1 = {};
    __builtin_amdgcn_s_setprio(1);
#pragma unroll
    for (int ks = 0; ks < 4; ++ks) {
      const int d32 = ks >> 1, g4k = (ks & 1) * 2 + hi;
      bf16x8 kf = *(const bf16x8*)&Klb[((b4 * 2 + d32) * 64 + m16 + 16 * g4k) * 8];
      s0 = mfma32(kf, qf[ks], s0);
    }
#pragma unroll
    for (int ks = 0; ks < 4; ++ks) {
      const int d32 = ks >> 1, g4k = (ks & 1) * 2 + hi;
      bf16x8 kf = *(const bf16x8*)&Klb[2048 + ((b4 * 2 + d32) * 64 + m16 + 16 * g4k) * 8];
      s1 = mfma32(kf, qf[ks], s1);
    }
    __builtin_amdgcn_s_setprio(0);

#pragma unroll
    for (int u = 0; u < 2; ++u) {
      const bf16* const Vl = Vlb + u * 2048;
      const f32x16& s = u == 0 ? s0 : s1;
      float e[16];
#pragma unroll
      for (int r = 0; r < 16; ++r) e[r] = fexp2(s[r]);
      {
        float a0 = e[0] + e[1], a1 = e[2] + e[3], a2 = e[4] + e[5], a3 = e[6] + e[7];
        float a4 = e[8] + e[9], a5 = e[10] + e[11], a6 = e[12] + e[13], a7 = e[14] + e[15];
        lrow += ((a0 + a1) + (a2 + a3)) + ((a4 + a5) + (a6 + a7));
      }
      bf16x8 bP[2];
#pragma unroll
      for (int c = 0; c < 2; ++c) {
        unsigned P0 = pk2(e[8 * c + 0], e[8 * c + 1]);
        unsigned P1 = pk2(e[8 * c + 2], e[8 * c + 3]);
        unsigned P2 = pk2(e[8 * c + 4], e[8 * c + 5]);
        unsigned P3 = pk2(e[8 * c + 6], e[8 * c + 7]);
        plswap(P0, P2);
        plswap(P1, P3);
        alignas(16) unsigned pw[4] = {P0, P1, P2, P3};
        bP[c] = *(const bf16x8*)pw;
      }
      __builtin_amdgcn_s_setprio(1);
#pragma unroll
      for (int dtile = 0; dtile < 2; ++dtile) {
        const int dt = dtile * 2 + b4;
#pragma unroll
        for (int c = 0; c < 2; ++c) {
          bf16x8 av = *(const bf16x8*)&Vl[(dt * 64 + m16 + 16 * (2 * c + hi)) * 8];
          oacc[dtile] = mfma32(av, bP[c], oacc[dtile]);
        }
      }
      __builtin_amdgcn_s_setprio(0);
    }
    __syncthreads();
  }

  lrow += __shfl_xor(lrow, 32);

  float* const Os = (float*)smem;              // [8][16][64]
  float* const Ls = (float*)(smem + 32768);    // [4][32]
  if (g == 1) {
#pragma unroll
    for (int dtile = 0; dtile < 2; ++dtile)
#pragma unroll
      for (int r = 0; r < 16; ++r)
        Os[((qw * 2 + dtile) * 16 + r) * 64 + lane] = oacc[dtile][r];
    if (hi == 0) Ls[qw * 32 + l31] = lrow;
  }
  __syncthreads();
  if (g == 0) {
    const float inv = 1.f / (lrow + Ls[qw * 32 + l31]);
    const int sQ = b * 128 + qt * 8 + qw * 2 + b4;
#pragma unroll
    for (int dtile = 0; dtile < 2; ++dtile) {
      const int k32 = h * 2 + dtile;
#pragma unroll
      for (int j = 0; j < 8; ++j) {
        const int r = 2 * j;
        float o0 = oacc[dtile][r] + Os[((qw * 2 + dtile) * 16 + r) * 64 + lane];
        float o1 = oacc[dtile][r + 1] + Os[((qw * 2 + dtile) * 16 + r + 1) * 64 + lane];
        unsigned pv = pk2(o0 * inv, o1 * inv);
        size_t off = ((size_t)sQ * 32 + k32) * 512 + (m16 + 16 * (r >> 2)) * 8 + 4 * hi + (r & 3);
        *(unsigned*)(Lab + off) = pv;
      }
    }
  }
}

// ---------------- Final GEMM: dbuf + counted vmcnt, XCD swizzle ----------------
__global__ __launch_bounds__(256) void out_gemm(const bf16* __restrict__ Lab,
                                                const bf16* __restrict__ Lwo,
                                                const float* __restrict__ bo,
                                                float* __restrict__ out) {
  __shared__ alignas(16) bf16 Al[2][8192];
  __shared__ alignas(16) bf16 Bl[2][4096];
  const int t = threadIdx.x, lane = t & 63, w = t >> 6;
  const int m16 = lane & 15, g4 = lane >> 4;
  const int bid = blockIdx.y * 16 + blockIdx.x;
  const int logical = (bid & 7) * 64 + (bid >> 3);
  const int nt = logical & 15, mt = logical >> 4;
  const int wm = w >> 1, wn = w & 1;
  f32x4 acc[4][2] = {};

#pragma unroll
  for (int ii = 0; ii < 4; ++ii) {
    int s = w * 4 + ii;
    gload16(Lab + (((size_t)(mt * 8 + (s >> 1))) * 32 + (s & 1)) * 512 + lane * 8, (void*)&Al[0][s * 512]);
  }
#pragma unroll
  for (int ii = 0; ii < 2; ++ii) {
    int s = w * 2 + ii;
    gload16(Lwo + (((size_t)(nt * 4 + (s >> 1))) * 32 + (s & 1)) * 512 + lane * 8, (void*)&Bl[0][s * 512]);
  }

  int cur = 0;
  for (int slab = 0; slab < 16; ++slab) {
    __builtin_amdgcn_s_barrier();
    __builtin_amdgcn_sched_barrier(0);
    if (slab < 15) {
      const int nb = cur ^ 1, ns = slab + 1;
#pragma unroll
      for (int ii = 0; ii < 4; ++ii) {
        int s = w * 4 + ii;
        gload16(Lab + (((size_t)(mt * 8 + (s >> 1))) * 32 + ns * 2 + (s & 1)) * 512 + lane * 8,
                (void*)&Al[nb][s * 512]);
      }
#pragma unroll
      for (int ii = 0; ii < 2; ++ii) {
        int s = w * 2 + ii;
        gload16(Lwo + (((size_t)(nt * 4 + (s >> 1))) * 32 + ns * 2 + (s & 1)) * 512 + lane * 8,
                (void*)&Bl[nb][s * 512]);
      }
      asm volatile("s_waitcnt vmcnt(6)" ::: "memory");
    } else {
      asm volatile("s_waitcnt vmcnt(0)" ::: "memory");
    }
    __builtin_amdgcn_sched_barrier(0);
    __builtin_amdgcn_s_barrier();
    __builtin_amdgcn_sched_barrier(0);
#pragma unroll
    for (int c = 0; c < 2; ++c) {
      bf16x8 aA[4], bW[2];
#pragma unroll
      for (int i = 0; i < 4; ++i) aA[i] = *(const bf16x8*)&Al[cur][((wm * 4 + i) * 2 + c) * 512 + lane * 8];
#pragma unroll
      for (int j = 0; j < 2; ++j) bW[j] = *(const bf16x8*)&Bl[cur][((wn * 2 + j) * 2 + c) * 512 + lane * 8];
      __builtin_amdgcn_s_setprio(1);
#pragma unroll
      for (int i = 0; i < 4; ++i)
#pragma unroll
        for (int j = 0; j < 2; ++j) acc[i][j] = mfma16(aA[i], bW[j], acc[i][j]);
      __builtin_amdgcn_s_setprio(0);
    }
    cur ^= 1;
  }
#pragma unroll
  for (int j = 0; j < 2; ++j) {
    int n = nt * 64 + wn * 32 + j * 16 + m16;
    float bb = bo[n];
#pragma unroll
    for (int i = 0; i < 4; ++i) {
      int seqb = mt * 128 + wm * 64 + i * 16 + g4 * 4;
#pragma unroll
      for (int r = 0; r < 4; ++r) out[(size_t)(seqb + r) * 1024 + n] = acc[i][j][r] + bb;
    }
  }
}

extern "C" void kernel_launch(void* const* d_in, const int* in_sizes, int n_in,
                              void* d_out, int out_size, void* d_ws, size_t ws_size,
                              hipStream_t stream) {
  const float* query = (const float*)d_in[0];
  const float* key   = (const float*)d_in[1];
  const float* value = (const float*)d_in[2];
  const float* Wq = (const float*)d_in[3];
  const float* bq = (const float*)d_in[4];
  const float* Wk = (const float*)d_in[5];
  const float* bk = (const float*)d_in[6];
  const float* Wv = (const float*)d_in[7];
  const float* bv = (const float*)d_in[8];
  const float* Wo = (const float*)d_in[9];
  const float* bo = (const float*)d_in[10];
  float* out = (float*)d_out;

  bf16* Lw  = (bf16*)d_ws;
  bf16* Lwo = Lw + 3ull * 1048576;
  bf16* Lx  = Lwo + 1048576;
  bf16* Lq  = Lx + 3ull * 4194304;
  bf16* Lk  = Lq + 4194304;
  bf16* Lv  = Lk + 4194304;
  bf16* Lab = Lv + 4194304;

  cast_all<<<dim3(256, 7), 256, 0, stream>>>(query, key, value, Wq, Wk, Wv, Wo, Lx, Lw, Lwo);
  qkv_gemm<<<384, 512, 0, stream>>>(Lw, Lx, bq, bk, bv, Lq, Lk, Lv);
  flash<<<512, 512, 0, stream>>>(Lq, Lk, Lv, Lab);
  out_gemm<<<dim3(16, 32), 256, 0, stream>>>(Lab, Lwo, bo, out);
}